// Round 1
// baseline (1021.882 us; speedup 1.0000x reference)
//
#include <hip/hip_runtime.h>
#include <hip/hip_bf16.h>
#include <cstddef>

#define D_MODEL 256
#define N_TOK   16384
#define NHEAD   8
#define HDIM    32
#define LNEIGH  32
#define DFF     2048
#define FF_CHUNK 256

// ---------------------------------------------------------------------------
// Generic fp32 SGEMM: out[M,N] = epilogue(A[M,K] @ W[K,N])
// epilogue: v = (acc + bias[n]) * outscale + resid[m,n]; relu; accum
// 64x64 tile, 256 threads, 4x4 per thread.
// ---------------------------------------------------------------------------
__global__ __launch_bounds__(256) void sgemm_kernel(
    const float* __restrict__ A, int lda,
    const float* __restrict__ W, int ldw,
    const float* __restrict__ bias,
    const float* __restrict__ resid,
    float* __restrict__ out,
    int M, int N, int K,
    float outscale, int relu, int accum)
{
    __shared__ float As[16][65];   // [k][m], padded
    __shared__ float Bs[16][64];   // [k][n]

    const int tid = threadIdx.x;
    const int bm = blockIdx.y * 64;
    const int bn = blockIdx.x * 64;
    const int tx = tid & 15;   // n-group
    const int ty = tid >> 4;   // m-group

    float acc[4][4] = {};

    for (int k0 = 0; k0 < K; k0 += 16) {
        #pragma unroll
        for (int i = 0; i < 4; ++i) {
            int idx = tid + i * 256;           // 0..1023
            int m  = idx >> 4;
            int kk = idx & 15;
            As[kk][m] = A[(size_t)(bm + m) * lda + k0 + kk];
        }
        #pragma unroll
        for (int i = 0; i < 4; ++i) {
            int idx = tid + i * 256;
            int kk = idx >> 6;
            int n  = idx & 63;
            Bs[kk][n] = W[(size_t)(k0 + kk) * ldw + bn + n];
        }
        __syncthreads();
        #pragma unroll
        for (int kk = 0; kk < 16; ++kk) {
            float ra[4], rb[4];
            #pragma unroll
            for (int i = 0; i < 4; ++i) ra[i] = As[kk][ty * 4 + i];
            #pragma unroll
            for (int j = 0; j < 4; ++j) rb[j] = Bs[kk][tx * 4 + j];
            #pragma unroll
            for (int i = 0; i < 4; ++i)
                #pragma unroll
                for (int j = 0; j < 4; ++j)
                    acc[i][j] += ra[i] * rb[j];
        }
        __syncthreads();
    }

    #pragma unroll
    for (int i = 0; i < 4; ++i) {
        int m = bm + ty * 4 + i;
        #pragma unroll
        for (int j = 0; j < 4; ++j) {
            int n = bn + tx * 4 + j;
            float v = acc[i][j];
            if (bias)  v += bias[n];
            v *= outscale;
            if (resid) v += resid[(size_t)m * N + n];
            if (relu)  v = fmaxf(v, 0.0f);
            float* o = &out[(size_t)m * N + n];
            if (accum) *o += v; else *o = v;
        }
    }
}

// ---------------------------------------------------------------------------
// Gathered local attention. One block (256 thr) per query.
// q already includes 1/sqrt(hd) scale (applied in QKV epilogue).
// ---------------------------------------------------------------------------
__global__ __launch_bounds__(256) void attn_kernel(
    const float* __restrict__ q,
    const float* __restrict__ k,
    const float* __restrict__ v,
    const int* __restrict__ index_pair,
    const int* __restrict__ key_batch_cnt,
    const int* __restrict__ ipb,
    float* __restrict__ out)
{
    const int n   = blockIdx.x;
    const int tid = threadIdx.x;

    __shared__ float qs[256];
    __shared__ float wsm[256];   // attention weights [h][l]
    __shared__ int   gidx[32];   // gather index, -1 = invalid

    if (tid < 32) {
        int raw = index_pair[(size_t)n * LNEIGH + tid];
        int b = ipb[n];
        int off = 0;
        for (int i = 0; i < b; ++i) off += key_batch_cnt[i];
        gidx[tid] = (raw >= 0) ? (raw + off) : -1;
    }
    qs[tid] = q[(size_t)n * D_MODEL + tid];
    __syncthreads();

    const int h = tid >> 5;
    const int l = tid & 31;
    int gi = gidx[l];
    float logit = -1e9f;
    if (gi >= 0) {
        const float* kr = k + (size_t)gi * D_MODEL + h * HDIM;
        const float* qr = qs + h * HDIM;
        float s = 0.0f;
        #pragma unroll
        for (int d = 0; d < HDIM; ++d) s += qr[d] * kr[d];
        logit = s;
    }
    // softmax across the 32-lane neighbor group (masks <32 stay in-group)
    float mx = logit;
    #pragma unroll
    for (int o = 16; o >= 1; o >>= 1) mx = fmaxf(mx, __shfl_xor(mx, o));
    float p = expf(logit - mx);
    float ssum = p;
    #pragma unroll
    for (int o = 16; o >= 1; o >>= 1) ssum += __shfl_xor(ssum, o);
    wsm[tid] = p / ssum;
    __syncthreads();

    // PV: thread d computes out[n,d]; v reads coalesced across lanes.
    const int d  = tid;
    const int h2 = d >> 5;
    float o = 0.0f;
    #pragma unroll 8
    for (int l2 = 0; l2 < LNEIGH; ++l2) {
        int gi2 = gidx[l2];
        if (gi2 < 0) gi2 = 0;   // ref gathers row 0 for invalid (weight 0)
        o += wsm[(h2 << 5) | l2] * v[(size_t)gi2 * D_MODEL + d];
    }
    out[(size_t)n * D_MODEL + d] = o;
}

// ---------------------------------------------------------------------------
// LayerNorm over rows of 256. One block (256 thr) per row.
// ---------------------------------------------------------------------------
__global__ __launch_bounds__(256) void ln_kernel(
    const float* __restrict__ x,
    const float* __restrict__ g,
    const float* __restrict__ b,
    float* __restrict__ out)
{
    const int row = blockIdx.x;
    const int tid = threadIdx.x;
    float val = x[(size_t)row * D_MODEL + tid];
    float s = val, s2 = val * val;
    #pragma unroll
    for (int o = 32; o >= 1; o >>= 1) {
        s  += __shfl_xor(s,  o);
        s2 += __shfl_xor(s2, o);
    }
    __shared__ float ss[4], ss2[4];
    const int wid = tid >> 6;
    if ((tid & 63) == 0) { ss[wid] = s; ss2[wid] = s2; }
    __syncthreads();
    s  = ss[0] + ss[1] + ss[2] + ss[3];
    s2 = ss2[0] + ss2[1] + ss2[2] + ss2[3];
    float mu  = s * (1.0f / D_MODEL);
    float var = s2 * (1.0f / D_MODEL) - mu * mu;
    float inv = rsqrtf(var + 1e-5f);
    out[(size_t)row * D_MODEL + tid] = (val - mu) * inv * g[tid] + b[tid];
}

// ---------------------------------------------------------------------------
extern "C" void kernel_launch(void* const* d_in, const int* in_sizes, int n_in,
                              void* d_out, int out_size, void* d_ws, size_t ws_size,
                              hipStream_t stream)
{
    const float* src = (const float*)d_in[0];
    const int*   index_pair = (const int*)d_in[1];
    // d_in[2] = query_batch_cnt (unused)
    const int*   kbc = (const int*)d_in[3];
    const int*   ipb = (const int*)d_in[4];
    const float* Wq = (const float*)d_in[5];
    const float* bq = (const float*)d_in[6];
    const float* Wk = (const float*)d_in[7];
    const float* bk = (const float*)d_in[8];
    const float* Wv = (const float*)d_in[9];
    const float* bv = (const float*)d_in[10];
    const float* Wo = (const float*)d_in[11];
    const float* bo = (const float*)d_in[12];
    const float* W1 = (const float*)d_in[13];
    const float* b1 = (const float*)d_in[14];
    const float* W2 = (const float*)d_in[15];
    const float* b2 = (const float*)d_in[16];
    const float* g1 = (const float*)d_in[17];
    const float* be1 = (const float*)d_in[18];
    const float* g2 = (const float*)d_in[19];
    const float* be2 = (const float*)d_in[20];
    float* out = (float*)d_out;

    const size_t BUF = (size_t)N_TOK * D_MODEL * sizeof(float);  // 16.78 MB
    char* ws = (char*)d_ws;
    float* qb   = (float*)(ws + 0 * BUF);
    float* kb   = (float*)(ws + 1 * BUF);
    float* vb   = (float*)(ws + 2 * BUF);
    float* attn = (float*)(ws + 3 * BUF);
    float* yb = qb;    // reuse: post-Wo + residual
    float* xb = kb;    // reuse: LN1 output
    float* zb = vb;    // reuse: FFN accumulator
    float* hc = attn;  // reuse: FFN hidden chunk (after attn consumed)

    const dim3 blk(256);
    const dim3 g_gemm(D_MODEL / 64, N_TOK / 64);   // (4, 256)
    const float qscale = 0.17677669529663687f;     // 1/sqrt(32)

    // QKV projections
    sgemm_kernel<<<g_gemm, blk, 0, stream>>>(src, 256, Wq, 256, bq, nullptr, qb,
                                             N_TOK, 256, 256, qscale, 0, 0);
    sgemm_kernel<<<g_gemm, blk, 0, stream>>>(src, 256, Wk, 256, bk, nullptr, kb,
                                             N_TOK, 256, 256, 1.0f, 0, 0);
    sgemm_kernel<<<g_gemm, blk, 0, stream>>>(src, 256, Wv, 256, bv, nullptr, vb,
                                             N_TOK, 256, 256, 1.0f, 0, 0);

    // gathered attention
    attn_kernel<<<N_TOK, blk, 0, stream>>>(qb, kb, vb, index_pair, kbc, ipb, attn);

    // output projection + residual(src)
    sgemm_kernel<<<g_gemm, blk, 0, stream>>>(attn, 256, Wo, 256, bo, src, yb,
                                             N_TOK, 256, 256, 1.0f, 0, 0);
    // LN1
    ln_kernel<<<N_TOK, blk, 0, stream>>>(yb, g1, be1, xb);

    // FFN, chunked over 256-wide hidden slices
    const dim3 g_ff1(FF_CHUNK / 64, N_TOK / 64);
    for (int c = 0; c < DFF / FF_CHUNK; ++c) {
        sgemm_kernel<<<g_ff1, blk, 0, stream>>>(
            xb, 256, W1 + c * FF_CHUNK, DFF, b1 + c * FF_CHUNK, nullptr, hc,
            N_TOK, FF_CHUNK, 256, 1.0f, 1 /*relu*/, 0);
        sgemm_kernel<<<g_gemm, blk, 0, stream>>>(
            hc, FF_CHUNK, W2 + (size_t)c * FF_CHUNK * 256, 256,
            (c == 0) ? b2 : nullptr, (c == 0) ? xb : nullptr, zb,
            N_TOK, 256, FF_CHUNK, 1.0f, 0, (c > 0) ? 1 : 0);
    }

    // LN2 -> output
    ln_kernel<<<N_TOK, blk, 0, stream>>>(zb, g2, be2, out);
}

// Round 2
// 348.818 us; speedup vs baseline: 2.9296x; 2.9296x over previous
//
#include <hip/hip_runtime.h>
#include <hip/hip_bf16.h>
#include <cstddef>
#include <cstdint>

#define D_MODEL 256
#define N_TOK   16384
#define NHEAD   8
#define HDIM    32
#define LNEIGH  32
#define DFF     2048
#define FF_CHUNK 512

typedef short bf16x8 __attribute__((ext_vector_type(8)));
typedef float f32x4  __attribute__((ext_vector_type(4)));

__device__ __forceinline__ float b2f(short s) {
    unsigned u = ((unsigned)(unsigned short)s) << 16;
    return __builtin_bit_cast(float, u);
}

// global -> LDS async copy, 16B per lane. LDS dest must be wave-uniform base.
__device__ __forceinline__ void gload_lds16(const void* g, void* l) {
    auto* gp = reinterpret_cast<const __attribute__((address_space(1))) uint32_t*>(
        reinterpret_cast<uintptr_t>(g));
    auto* lp = reinterpret_cast<__attribute__((address_space(3))) uint32_t*>(
        reinterpret_cast<uintptr_t>(l));
    __builtin_amdgcn_global_load_lds(gp, lp, 16, 0, 0);
}

// ---------------------------------------------------------------------------
// bf16 MFMA GEMM:  C[M,N] = A[M,K] @ Bt[N,K]^T  (both row-major bf16)
// 128x128 tile, 256 threads (4 waves), each wave a 64x64 quadrant (4x4 frags
// of 16x16x32). fp32 epilogue: +bias[n], +resid[m,n], relu, accum into outf,
// optional bf16 store to outb.
// ---------------------------------------------------------------------------
__global__ __launch_bounds__(256) void gemm_bt(
    const __hip_bfloat16* __restrict__ A, int lda,
    const __hip_bfloat16* __restrict__ Bt, int ldb,
    const float* __restrict__ bias,
    const float* __restrict__ resid,
    float* __restrict__ outf,
    __hip_bfloat16* __restrict__ outb,
    int M, int N, int K, int relu, int accum)
{
    __shared__ short Asm[128 * 32];
    __shared__ short Bsm[128 * 32];

    const int tid  = threadIdx.x;
    const int lane = tid & 63;
    const int wid  = tid >> 6;           // 0..3
    const int wr   = wid >> 1;           // wave row quadrant
    const int wc   = wid & 1;            // wave col quadrant
    const int bm   = blockIdx.y * 128;
    const int bn   = blockIdx.x * 128;

    f32x4 acc[4][4] = {};

    const int srow = (lane >> 2);        // 0..15 row within 16-row stripe
    const int seg  = (lane & 3) * 8;     // element offset of 16B segment

    for (int k0 = 0; k0 < K; k0 += 32) {
        #pragma unroll
        for (int t = 0; t < 2; ++t) {
            int rbase = wid * 32 + t * 16;
            const __hip_bfloat16* ag = A  + (size_t)(bm + rbase + srow) * lda + k0 + seg;
            const __hip_bfloat16* bg = Bt + (size_t)(bn + rbase + srow) * ldb + k0 + seg;
            gload_lds16(ag, &Asm[rbase * 32]);
            gload_lds16(bg, &Bsm[rbase * 32]);
        }
        __syncthreads();

        bf16x8 a[4], b[4];
        #pragma unroll
        for (int i = 0; i < 4; ++i)
            a[i] = *(const bf16x8*)&Asm[(wr * 64 + i * 16 + (lane & 15)) * 32 + (lane >> 4) * 8];
        #pragma unroll
        for (int j = 0; j < 4; ++j)
            b[j] = *(const bf16x8*)&Bsm[(wc * 64 + j * 16 + (lane & 15)) * 32 + (lane >> 4) * 8];
        #pragma unroll
        for (int i = 0; i < 4; ++i)
            #pragma unroll
            for (int j = 0; j < 4; ++j)
                acc[i][j] = __builtin_amdgcn_mfma_f32_16x16x32_bf16(a[i], b[j], acc[i][j], 0, 0, 0);
        __syncthreads();
    }

    // epilogue: C/D layout col=lane&15, row=(lane>>4)*4+r  [m89 verified]
    #pragma unroll
    for (int i = 0; i < 4; ++i) {
        int rbase = bm + wr * 64 + i * 16 + ((lane >> 4) << 2);
        #pragma unroll
        for (int j = 0; j < 4; ++j) {
            int col = bn + wc * 64 + j * 16 + (lane & 15);
            float bval = bias ? bias[col] : 0.0f;
            #pragma unroll
            for (int r = 0; r < 4; ++r) {
                int row = rbase + r;
                float v = acc[i][j][r] + bval;
                size_t o = (size_t)row * N + col;
                if (resid) v += resid[o];
                if (relu)  v = fmaxf(v, 0.0f);
                if (outf) { if (accum) outf[o] += v; else outf[o] = v; }
                if (outb) outb[o] = __float2bfloat16(v);
            }
        }
    }
}

// ---------------------------------------------------------------------------
// fp32 -> bf16 elementwise (vectorized)
// ---------------------------------------------------------------------------
__global__ __launch_bounds__(256) void cvt_f2b(
    const float* __restrict__ x, __hip_bfloat16* __restrict__ y, int n)
{
    int i = (blockIdx.x * 256 + threadIdx.x) * 4;
    if (i >= n) return;
    float4 v = *(const float4*)(x + i);
    y[i + 0] = __float2bfloat16(v.x);
    y[i + 1] = __float2bfloat16(v.y);
    y[i + 2] = __float2bfloat16(v.z);
    y[i + 3] = __float2bfloat16(v.w);
}

// W[K][N] fp32 -> Wt[N][K] bf16, with scale
__global__ __launch_bounds__(256) void cvt_wt(
    const float* __restrict__ W, __hip_bfloat16* __restrict__ Wt,
    int K, int N, float scale)
{
    int i = blockIdx.x * 256 + threadIdx.x;
    if (i >= N * K) return;
    int n = i / K;
    int k = i - n * K;
    Wt[i] = __float2bfloat16(W[(size_t)k * N + n] * scale);
}

__global__ __launch_bounds__(768) void make_bqkv(
    const float* __restrict__ bq, const float* __restrict__ bk,
    const float* __restrict__ bv, float* __restrict__ o, float qs)
{
    int i = threadIdx.x;
    if (i < 256)      o[i] = bq[i] * qs;
    else if (i < 512) o[i] = bk[i - 256];
    else              o[i] = bv[i - 512];
}

// ---------------------------------------------------------------------------
// Gathered local attention, bf16 K/V. One block (256 thr) per query.
// qkv layout: [N_TOK][768] bf16 (q | k | v). q pre-scaled by 1/sqrt(hd).
// ---------------------------------------------------------------------------
__global__ __launch_bounds__(256) void attn_kernel(
    const __hip_bfloat16* __restrict__ qkv,
    const int* __restrict__ index_pair,
    const int* __restrict__ key_batch_cnt,
    const int* __restrict__ ipb,
    __hip_bfloat16* __restrict__ out)
{
    // XCD swizzle: consecutive 2048-query chunk per XCD -> one batch's K/V
    // (4 MB bf16) stays in that XCD's L2.
    const int blk = blockIdx.x;
    const int n   = (blk & 7) * 2048 + (blk >> 3);
    const int tid = threadIdx.x;

    __shared__ float qs[256];
    __shared__ float wsm[256];   // attn weights [h][l]
    __shared__ int   gidx[32];

    if (tid < 32) {
        int raw = index_pair[(size_t)n * LNEIGH + tid];
        int b = ipb[n];
        int off = 0;
        for (int i = 0; i < b; ++i) off += key_batch_cnt[i];
        gidx[tid] = (raw >= 0) ? (raw + off) : -1;
    }
    qs[tid] = __bfloat162float(qkv[(size_t)n * 768 + tid]);
    __syncthreads();

    const int h = tid >> 5;
    const int l = tid & 31;
    int gi = gidx[l];
    float logit = -1e9f;
    if (gi >= 0) {
        const bf16x8* kp = (const bf16x8*)(qkv + (size_t)gi * 768 + 256 + h * HDIM);
        float s = 0.0f;
        #pragma unroll
        for (int u = 0; u < 4; ++u) {
            bf16x8 kv8 = kp[u];
            #pragma unroll
            for (int j = 0; j < 8; ++j)
                s += qs[h * HDIM + u * 8 + j] * b2f(kv8[j]);
        }
        logit = s;
    }
    float mx = logit;
    #pragma unroll
    for (int o = 16; o >= 1; o >>= 1) mx = fmaxf(mx, __shfl_xor(mx, o));
    float p = expf(logit - mx);
    float ssum = p;
    #pragma unroll
    for (int o = 16; o >= 1; o >>= 1) ssum += __shfl_xor(ssum, o);
    wsm[tid] = p / ssum;
    __syncthreads();

    const int d  = tid;
    const int h2 = d >> 5;
    float o = 0.0f;
    #pragma unroll 8
    for (int l2 = 0; l2 < LNEIGH; ++l2) {
        int gi2 = gidx[l2];
        if (gi2 < 0) gi2 = 0;   // ref gathers global row 0 for invalid (weight ~0)
        o += wsm[(h2 << 5) | l2] * __bfloat162float(qkv[(size_t)gi2 * 768 + 512 + d]);
    }
    out[(size_t)n * D_MODEL + d] = __float2bfloat16(o);
}

// ---------------------------------------------------------------------------
// LayerNorm over rows of 256; optional fp32 + bf16 outputs.
// ---------------------------------------------------------------------------
__global__ __launch_bounds__(256) void ln_kernel(
    const float* __restrict__ x,
    const float* __restrict__ g,
    const float* __restrict__ b,
    float* __restrict__ outf,
    __hip_bfloat16* __restrict__ outb)
{
    const int row = blockIdx.x;
    const int tid = threadIdx.x;
    float val = x[(size_t)row * D_MODEL + tid];
    float s = val, s2 = val * val;
    #pragma unroll
    for (int o = 32; o >= 1; o >>= 1) {
        s  += __shfl_xor(s,  o);
        s2 += __shfl_xor(s2, o);
    }
    __shared__ float ss[4], ss2[4];
    const int wid = tid >> 6;
    if ((tid & 63) == 0) { ss[wid] = s; ss2[wid] = s2; }
    __syncthreads();
    s  = ss[0] + ss[1] + ss[2] + ss[3];
    s2 = ss2[0] + ss2[1] + ss2[2] + ss2[3];
    float mu  = s * (1.0f / D_MODEL);
    float var = s2 * (1.0f / D_MODEL) - mu * mu;
    float inv = rsqrtf(var + 1e-5f);
    float r = (val - mu) * inv * g[tid] + b[tid];
    if (outf) outf[(size_t)row * D_MODEL + tid] = r;
    if (outb) outb[(size_t)row * D_MODEL + tid] = __float2bfloat16(r);
}

// ---------------------------------------------------------------------------
extern "C" void kernel_launch(void* const* d_in, const int* in_sizes, int n_in,
                              void* d_out, int out_size, void* d_ws, size_t ws_size,
                              hipStream_t stream)
{
    const float* src = (const float*)d_in[0];
    const int*   index_pair = (const int*)d_in[1];
    const int*   kbc = (const int*)d_in[3];
    const int*   ipb = (const int*)d_in[4];
    const float* Wq = (const float*)d_in[5];
    const float* bq = (const float*)d_in[6];
    const float* Wk = (const float*)d_in[7];
    const float* bk = (const float*)d_in[8];
    const float* Wv = (const float*)d_in[9];
    const float* bv = (const float*)d_in[10];
    const float* Wo = (const float*)d_in[11];
    const float* bo = (const float*)d_in[12];
    const float* W1 = (const float*)d_in[13];
    const float* b1 = (const float*)d_in[14];
    const float* W2 = (const float*)d_in[15];
    const float* b2 = (const float*)d_in[16];
    const float* g1 = (const float*)d_in[17];
    const float* be1 = (const float*)d_in[18];
    const float* g2 = (const float*)d_in[19];
    const float* be2 = (const float*)d_in[20];
    float* out = (float*)d_out;

    char* ws = (char*)d_ws;
    // byte offsets (all 256-aligned)
    const size_t O_SRCBF = 0;                       // 8.4 MB  (later: attn_bf)
    const size_t O_QKV   = 8388608;                 // 25.2 MB (later: x_bf)
    const size_t O_Y     = 33554432;                // 16.8 MB (y, later z)
    const size_t O_X     = 50331648;                // 16.8 MB (x fp32)
    const size_t O_H     = 67108864;                // 16.8 MB (FFN hidden chunk)
    const size_t O_WQKV  = 83886080;                // 768x256 bf16
    const size_t O_WO    = 84279296;                // 256x256 bf16
    const size_t O_W1    = 84410368;                // 2048x256 bf16
    const size_t O_W2    = 85458944;                // 256x2048 bf16
    const size_t O_BQKV  = 86507520;                // 768 fp32

    __hip_bfloat16* src_bf  = (__hip_bfloat16*)(ws + O_SRCBF);
    __hip_bfloat16* attn_bf = (__hip_bfloat16*)(ws + O_SRCBF);
    __hip_bfloat16* qkv     = (__hip_bfloat16*)(ws + O_QKV);
    __hip_bfloat16* x_bf    = (__hip_bfloat16*)(ws + O_QKV);
    float*          yb      = (float*)(ws + O_Y);
    float*          zb      = (float*)(ws + O_Y);
    float*          xb      = (float*)(ws + O_X);
    __hip_bfloat16* hc      = (__hip_bfloat16*)(ws + O_H);
    __hip_bfloat16* WqkvT   = (__hip_bfloat16*)(ws + O_WQKV);
    __hip_bfloat16* WoT     = (__hip_bfloat16*)(ws + O_WO);
    __hip_bfloat16* W1T     = (__hip_bfloat16*)(ws + O_W1);
    __hip_bfloat16* W2T     = (__hip_bfloat16*)(ws + O_W2);
    float*          bqkv    = (float*)(ws + O_BQKV);

    const dim3 blk(256);
    const float qscale = 0.17677669529663687f;  // 1/sqrt(32)

    // --- conversions ---
    cvt_f2b<<<(N_TOK * D_MODEL / 4 + 255) / 256, blk, 0, stream>>>(src, src_bf, N_TOK * D_MODEL);
    cvt_wt<<<(256 * 256 + 255) / 256, blk, 0, stream>>>(Wq, WqkvT,               256, 256, qscale);
    cvt_wt<<<(256 * 256 + 255) / 256, blk, 0, stream>>>(Wk, WqkvT + 256 * 256,   256, 256, 1.0f);
    cvt_wt<<<(256 * 256 + 255) / 256, blk, 0, stream>>>(Wv, WqkvT + 512 * 256,   256, 256, 1.0f);
    cvt_wt<<<(256 * 256 + 255) / 256, blk, 0, stream>>>(Wo, WoT,                 256, 256, 1.0f);
    cvt_wt<<<(DFF * 256 + 255) / 256, blk, 0, stream>>>(W1, W1T,                 256, DFF, 1.0f);
    cvt_wt<<<(DFF * 256 + 255) / 256, blk, 0, stream>>>(W2, W2T,                 DFF, 256, 1.0f);
    make_bqkv<<<1, 768, 0, stream>>>(bq, bk, bv, bqkv, qscale);

    // --- fused QKV projection: [16384,768] bf16 ---
    gemm_bt<<<dim3(6, 128), blk, 0, stream>>>(src_bf, 256, WqkvT, 256, bqkv,
                                              nullptr, nullptr, qkv,
                                              N_TOK, 768, 256, 0, 0);
    // --- gathered attention ---
    attn_kernel<<<N_TOK, blk, 0, stream>>>(qkv, index_pair, kbc, ipb, attn_bf);

    // --- output projection + residual(src) -> y fp32 ---
    gemm_bt<<<dim3(2, 128), blk, 0, stream>>>(attn_bf, 256, WoT, 256, bo,
                                              src, yb, nullptr,
                                              N_TOK, 256, 256, 0, 0);
    // --- LN1 -> x fp32 + x bf16 ---
    ln_kernel<<<N_TOK, blk, 0, stream>>>(yb, g1, be1, xb, x_bf);

    // --- FFN, chunked over 512-wide hidden slices ---
    for (int c = 0; c < DFF / FF_CHUNK; ++c) {
        gemm_bt<<<dim3(FF_CHUNK / 128, 128), blk, 0, stream>>>(
            x_bf, 256, W1T + (size_t)c * FF_CHUNK * 256, 256,
            b1 + c * FF_CHUNK, nullptr, nullptr, hc,
            N_TOK, FF_CHUNK, 256, 1 /*relu*/, 0);
        gemm_bt<<<dim3(2, 128), blk, 0, stream>>>(
            hc, FF_CHUNK, W2T + (size_t)c * FF_CHUNK, DFF,
            (c == 0) ? b2 : nullptr, (c == 0) ? xb : nullptr, zb, nullptr,
            N_TOK, 256, FF_CHUNK, 0, (c > 0) ? 1 : 0);
    }

    // --- LN2 -> out ---
    ln_kernel<<<N_TOK, blk, 0, stream>>>(zb, g2, be2, out, nullptr);
}

// Round 3
// 231.223 us; speedup vs baseline: 4.4195x; 1.5086x over previous
//
#include <hip/hip_runtime.h>
#include <hip/hip_bf16.h>
#include <cstddef>
#include <cstdint>

#define D_MODEL 256
#define N_TOK   16384
#define NHEAD   8
#define HDIM    32
#define LNEIGH  32
#define DFF     2048

typedef short bf16x8 __attribute__((ext_vector_type(8)));
typedef float f32x4  __attribute__((ext_vector_type(4)));

__device__ __forceinline__ float b2f(short s) {
    unsigned u = ((unsigned)(unsigned short)s) << 16;
    return __builtin_bit_cast(float, u);
}

// global -> LDS async copy, 16B per lane. LDS dest wave-uniform base + lane*16.
__device__ __forceinline__ void gload_lds16(const void* g, void* l) {
    auto* gp = reinterpret_cast<const __attribute__((address_space(1))) uint32_t*>(
        reinterpret_cast<uintptr_t>(g));
    auto* lp = reinterpret_cast<__attribute__((address_space(3))) uint32_t*>(
        reinterpret_cast<uintptr_t>(l));
    __builtin_amdgcn_global_load_lds(gp, lp, 16, 0, 0);
}

// ---------------------------------------------------------------------------
// bf16 MFMA GEMM, 128x128 tile, 256 threads (4 waves), wave = 64x64 quadrant.
// C = A[M,K] @ Bt[N,K]^T. Epilogue: +bias, +residf/+residb, relu, out f32/bf16.
// ---------------------------------------------------------------------------
__global__ __launch_bounds__(256) void gemm_bt(
    const __hip_bfloat16* __restrict__ A, int lda,
    const __hip_bfloat16* __restrict__ Bt, int ldb,
    const float* __restrict__ bias,
    const float* __restrict__ residf,
    const __hip_bfloat16* __restrict__ residb,
    float* __restrict__ outf,
    __hip_bfloat16* __restrict__ outb,
    int M, int N, int K, int relu, int accum)
{
    __shared__ short Asm[128 * 32];
    __shared__ short Bsm[128 * 32];

    const int tid  = threadIdx.x;
    const int lane = tid & 63;
    const int wid  = tid >> 6;
    const int wr   = wid >> 1;
    const int wc   = wid & 1;
    const int bm   = blockIdx.y * 128;
    const int bn   = blockIdx.x * 128;

    f32x4 acc[4][4] = {};
    const int srow = lane >> 2;
    const int seg  = (lane & 3) * 8;

    for (int k0 = 0; k0 < K; k0 += 32) {
        #pragma unroll
        for (int t = 0; t < 2; ++t) {
            int rbase = wid * 32 + t * 16;
            gload_lds16(A  + (size_t)(bm + rbase + srow) * lda + k0 + seg, &Asm[rbase * 32]);
            gload_lds16(Bt + (size_t)(bn + rbase + srow) * ldb + k0 + seg, &Bsm[rbase * 32]);
        }
        __syncthreads();

        bf16x8 a[4], b[4];
        #pragma unroll
        for (int i = 0; i < 4; ++i)
            a[i] = *(const bf16x8*)&Asm[(wr * 64 + i * 16 + (lane & 15)) * 32 + (lane >> 4) * 8];
        #pragma unroll
        for (int j = 0; j < 4; ++j)
            b[j] = *(const bf16x8*)&Bsm[(wc * 64 + j * 16 + (lane & 15)) * 32 + (lane >> 4) * 8];
        #pragma unroll
        for (int i = 0; i < 4; ++i)
            #pragma unroll
            for (int j = 0; j < 4; ++j)
                acc[i][j] = __builtin_amdgcn_mfma_f32_16x16x32_bf16(a[i], b[j], acc[i][j], 0, 0, 0);
        __syncthreads();
    }

    #pragma unroll
    for (int i = 0; i < 4; ++i) {
        int rbase = bm + wr * 64 + i * 16 + ((lane >> 4) << 2);
        #pragma unroll
        for (int j = 0; j < 4; ++j) {
            int col = bn + wc * 64 + j * 16 + (lane & 15);
            float bval = bias ? bias[col] : 0.0f;
            #pragma unroll
            for (int r = 0; r < 4; ++r) {
                int row = rbase + r;
                float v = acc[i][j][r] + bval;
                size_t o = (size_t)row * N + col;
                if (residf) v += residf[o];
                if (residb) v += __bfloat162float(residb[o]);
                if (relu)   v = fmaxf(v, 0.0f);
                if (outf) { if (accum) outf[o] += v; else outf[o] = v; }
                if (outb) outb[o] = __float2bfloat16(v);
            }
        }
    }
}

// ---------------------------------------------------------------------------
// BM=64 x BN=128 variant (for N=256 GEMMs: 2x the blocks of the 128-tile).
// 4 waves, each a 32x64 quadrant.
// ---------------------------------------------------------------------------
__global__ __launch_bounds__(256) void gemm_bt64(
    const __hip_bfloat16* __restrict__ A, int lda,
    const __hip_bfloat16* __restrict__ Bt, int ldb,
    const float* __restrict__ bias,
    const float* __restrict__ residf,
    const __hip_bfloat16* __restrict__ residb,
    float* __restrict__ outf,
    __hip_bfloat16* __restrict__ outb,
    int M, int N, int K, int relu, int accum)
{
    __shared__ short Asm[64 * 32];
    __shared__ short Bsm[128 * 32];

    const int tid  = threadIdx.x;
    const int lane = tid & 63;
    const int wid  = tid >> 6;
    const int wr   = wid >> 1;           // 0..1 (32-row half)
    const int wc   = wid & 1;            // 0..1 (64-col half)
    const int bm   = blockIdx.y * 64;
    const int bn   = blockIdx.x * 128;

    f32x4 acc[2][4] = {};
    const int srow = lane >> 2;
    const int seg  = (lane & 3) * 8;

    for (int k0 = 0; k0 < K; k0 += 32) {
        {
            int ra = wid * 16;
            gload_lds16(A + (size_t)(bm + ra + srow) * lda + k0 + seg, &Asm[ra * 32]);
        }
        #pragma unroll
        for (int t = 0; t < 2; ++t) {
            int rb = wid * 32 + t * 16;
            gload_lds16(Bt + (size_t)(bn + rb + srow) * ldb + k0 + seg, &Bsm[rb * 32]);
        }
        __syncthreads();

        bf16x8 a[2], b[4];
        #pragma unroll
        for (int i = 0; i < 2; ++i)
            a[i] = *(const bf16x8*)&Asm[(wr * 32 + i * 16 + (lane & 15)) * 32 + (lane >> 4) * 8];
        #pragma unroll
        for (int j = 0; j < 4; ++j)
            b[j] = *(const bf16x8*)&Bsm[(wc * 64 + j * 16 + (lane & 15)) * 32 + (lane >> 4) * 8];
        #pragma unroll
        for (int i = 0; i < 2; ++i)
            #pragma unroll
            for (int j = 0; j < 4; ++j)
                acc[i][j] = __builtin_amdgcn_mfma_f32_16x16x32_bf16(a[i], b[j], acc[i][j], 0, 0, 0);
        __syncthreads();
    }

    #pragma unroll
    for (int i = 0; i < 2; ++i) {
        int rbase = bm + wr * 32 + i * 16 + ((lane >> 4) << 2);
        #pragma unroll
        for (int j = 0; j < 4; ++j) {
            int col = bn + wc * 64 + j * 16 + (lane & 15);
            float bval = bias ? bias[col] : 0.0f;
            #pragma unroll
            for (int r = 0; r < 4; ++r) {
                int row = rbase + r;
                float v = acc[i][j][r] + bval;
                size_t o = (size_t)row * N + col;
                if (residf) v += residf[o];
                if (residb) v += __bfloat162float(residb[o]);
                if (relu)   v = fmaxf(v, 0.0f);
                if (outf) { if (accum) outf[o] += v; else outf[o] = v; }
                if (outb) outb[o] = __float2bfloat16(v);
            }
        }
    }
}

// ---------------------------------------------------------------------------
// fp32 -> bf16 elementwise
// ---------------------------------------------------------------------------
__global__ __launch_bounds__(256) void cvt_f2b(
    const float* __restrict__ x, __hip_bfloat16* __restrict__ y, int n)
{
    int i = (blockIdx.x * 256 + threadIdx.x) * 4;
    if (i >= n) return;
    float4 v = *(const float4*)(x + i);
    y[i + 0] = __float2bfloat16(v.x);
    y[i + 1] = __float2bfloat16(v.y);
    y[i + 2] = __float2bfloat16(v.z);
    y[i + 3] = __float2bfloat16(v.w);
}

// Tiled transpose: W[K][N] fp32 -> Wt[N][K] bf16 (coalesced both sides).
__global__ __launch_bounds__(256) void cvt_wt_tiled(
    const float* __restrict__ W, __hip_bfloat16* __restrict__ Wt,
    int K, int N, float scale)
{
    __shared__ float t[32][33];
    const int n0 = blockIdx.x * 32;
    const int k0 = blockIdx.y * 32;
    const int tx = threadIdx.x & 31;
    const int ty = threadIdx.x >> 5;
    #pragma unroll
    for (int i = 0; i < 32; i += 8)
        t[ty + i][tx] = W[(size_t)(k0 + ty + i) * N + n0 + tx];
    __syncthreads();
    #pragma unroll
    for (int i = 0; i < 32; i += 8)
        Wt[(size_t)(n0 + ty + i) * K + k0 + tx] = __float2bfloat16(t[tx][ty + i] * scale);
}

// Fused Wq/Wk/Wv transpose into WqkvT[768][256]; q columns pre-scaled.
__global__ __launch_bounds__(256) void cvt_w3_tiled(
    const float* __restrict__ Wa, const float* __restrict__ Wb,
    const float* __restrict__ Wc, __hip_bfloat16* __restrict__ Wt,
    float scale_a)
{
    __shared__ float t[32][33];
    const int n0 = blockIdx.x * 32;            // 0..767
    const int k0 = blockIdx.y * 32;            // 0..255
    const float* W = (n0 < 256) ? Wa : (n0 < 512 ? Wb : Wc);
    const float sc = (n0 < 256) ? scale_a : 1.0f;
    const int ncol = n0 & 255;
    const int tx = threadIdx.x & 31;
    const int ty = threadIdx.x >> 5;
    #pragma unroll
    for (int i = 0; i < 32; i += 8)
        t[ty + i][tx] = W[(size_t)(k0 + ty + i) * 256 + ncol + tx];
    __syncthreads();
    #pragma unroll
    for (int i = 0; i < 32; i += 8)
        Wt[(size_t)(n0 + ty + i) * 256 + k0 + tx] = __float2bfloat16(t[tx][ty + i] * sc);
}

__global__ __launch_bounds__(768) void make_bqkv(
    const float* __restrict__ bq, const float* __restrict__ bk,
    const float* __restrict__ bv, float* __restrict__ o, float qs)
{
    int i = threadIdx.x;
    if (i < 256)      o[i] = bq[i] * qs;
    else if (i < 512) o[i] = bk[i - 256];
    else              o[i] = bv[i - 512];
}

// ---------------------------------------------------------------------------
// Gathered local attention, bf16 qkv[N][768]. One block per query.
// ---------------------------------------------------------------------------
__global__ __launch_bounds__(256) void attn_kernel(
    const __hip_bfloat16* __restrict__ qkv,
    const int* __restrict__ index_pair,
    const int* __restrict__ key_batch_cnt,
    const int* __restrict__ ipb,
    __hip_bfloat16* __restrict__ out)
{
    const int blk = blockIdx.x;
    const int n   = (blk & 7) * 2048 + (blk >> 3);   // XCD swizzle
    const int tid = threadIdx.x;

    __shared__ float qs[256];
    __shared__ float wsm[256];
    __shared__ int   gidx[32];

    if (tid < 32) {
        int raw = index_pair[(size_t)n * LNEIGH + tid];
        int b = ipb[n];
        int off = 0;
        for (int i = 0; i < b; ++i) off += key_batch_cnt[i];
        gidx[tid] = (raw >= 0) ? (raw + off) : -1;
    }
    qs[tid] = __bfloat162float(qkv[(size_t)n * 768 + tid]);
    __syncthreads();

    const int h = tid >> 5;
    const int l = tid & 31;
    int gi = gidx[l];
    float logit = -1e9f;
    if (gi >= 0) {
        const bf16x8* kp = (const bf16x8*)(qkv + (size_t)gi * 768 + 256 + h * HDIM);
        float s = 0.0f;
        #pragma unroll
        for (int u = 0; u < 4; ++u) {
            bf16x8 kv8 = kp[u];
            #pragma unroll
            for (int j = 0; j < 8; ++j)
                s += qs[h * HDIM + u * 8 + j] * b2f(kv8[j]);
        }
        logit = s;
    }
    float mx = logit;
    #pragma unroll
    for (int o = 16; o >= 1; o >>= 1) mx = fmaxf(mx, __shfl_xor(mx, o));
    float p = expf(logit - mx);
    float ssum = p;
    #pragma unroll
    for (int o = 16; o >= 1; o >>= 1) ssum += __shfl_xor(ssum, o);
    wsm[tid] = p / ssum;
    __syncthreads();

    const int d  = tid;
    const int h2 = d >> 5;
    float o = 0.0f;
    #pragma unroll 8
    for (int l2 = 0; l2 < LNEIGH; ++l2) {
        int gi2 = gidx[l2];
        if (gi2 < 0) gi2 = 0;
        o += wsm[(h2 << 5) | l2] * __bfloat162float(qkv[(size_t)gi2 * 768 + 512 + d]);
    }
    out[(size_t)n * D_MODEL + d] = __float2bfloat16(o);
}

// ---------------------------------------------------------------------------
// LayerNorm rows of 256; optional fp32 + bf16 outputs.
// ---------------------------------------------------------------------------
__global__ __launch_bounds__(256) void ln_kernel(
    const float* __restrict__ x,
    const float* __restrict__ g,
    const float* __restrict__ b,
    float* __restrict__ outf,
    __hip_bfloat16* __restrict__ outb)
{
    const int row = blockIdx.x;
    const int tid = threadIdx.x;
    float val = x[(size_t)row * D_MODEL + tid];
    float s = val, s2 = val * val;
    #pragma unroll
    for (int o = 32; o >= 1; o >>= 1) {
        s  += __shfl_xor(s,  o);
        s2 += __shfl_xor(s2, o);
    }
    __shared__ float ss[4], ss2[4];
    const int wid = tid >> 6;
    if ((tid & 63) == 0) { ss[wid] = s; ss2[wid] = s2; }
    __syncthreads();
    s  = ss[0] + ss[1] + ss[2] + ss[3];
    s2 = ss2[0] + ss2[1] + ss2[2] + ss2[3];
    float mu  = s * (1.0f / D_MODEL);
    float var = s2 * (1.0f / D_MODEL) - mu * mu;
    float inv = rsqrtf(var + 1e-5f);
    float r = (val - mu) * inv * g[tid] + b[tid];
    if (outf) outf[(size_t)row * D_MODEL + tid] = r;
    if (outb) outb[(size_t)row * D_MODEL + tid] = __float2bfloat16(r);
}

// ---------------------------------------------------------------------------
extern "C" void kernel_launch(void* const* d_in, const int* in_sizes, int n_in,
                              void* d_out, int out_size, void* d_ws, size_t ws_size,
                              hipStream_t stream)
{
    const float* src = (const float*)d_in[0];
    const int*   index_pair = (const int*)d_in[1];
    const int*   kbc = (const int*)d_in[3];
    const int*   ipb = (const int*)d_in[4];
    const float* Wq = (const float*)d_in[5];
    const float* bq = (const float*)d_in[6];
    const float* Wk = (const float*)d_in[7];
    const float* bk = (const float*)d_in[8];
    const float* Wv = (const float*)d_in[9];
    const float* bv = (const float*)d_in[10];
    const float* Wo = (const float*)d_in[11];
    const float* bo = (const float*)d_in[12];
    const float* W1 = (const float*)d_in[13];
    const float* b1 = (const float*)d_in[14];
    const float* W2 = (const float*)d_in[15];
    const float* b2 = (const float*)d_in[16];
    const float* g1 = (const float*)d_in[17];
    const float* be1 = (const float*)d_in[18];
    const float* g2 = (const float*)d_in[19];
    const float* be2 = (const float*)d_in[20];
    float* out = (float*)d_out;

    char* ws = (char*)d_ws;
    const size_t O_SRCBF = 0;                    //  8.39 MB
    const size_t O_QKV   = 8388608;              // 25.17 MB
    const size_t O_ATTN  = 33554432;             //  8.39 MB
    const size_t O_Y     = 41943040;             // 16.78 MB (y fp32; z reuses)
    const size_t O_XBF   = 58720256;             //  8.39 MB
    const size_t O_H     = 67108864;             // up to 67.1 MB

    // pick FFN chunk size that fits ws
    int ffc = 512;
    size_t hbytes = (size_t)N_TOK * 512 * 2;
    if (ws_size >= O_H + (size_t)N_TOK * DFF * 2 + 4 * 1024 * 1024) {
        ffc = 2048; hbytes = (size_t)N_TOK * DFF * 2;
    } else if (ws_size >= O_H + (size_t)N_TOK * 1024 * 2 + 4 * 1024 * 1024) {
        ffc = 1024; hbytes = (size_t)N_TOK * 1024 * 2;
    }
    const size_t O_WQKV = O_H + hbytes;
    const size_t O_WO   = O_WQKV + 768 * 256 * 2;
    const size_t O_W1   = O_WO + 256 * 256 * 2;
    const size_t O_W2   = O_W1 + (size_t)DFF * 256 * 2;
    const size_t O_BQKV = O_W2 + (size_t)DFF * 256 * 2;

    __hip_bfloat16* src_bf  = (__hip_bfloat16*)(ws + O_SRCBF);
    __hip_bfloat16* qkv     = (__hip_bfloat16*)(ws + O_QKV);
    __hip_bfloat16* attn_bf = (__hip_bfloat16*)(ws + O_ATTN);
    float*          yb      = (float*)(ws + O_Y);
    float*          zb      = (float*)(ws + O_Y);      // reuse after LN1
    __hip_bfloat16* x_bf    = (__hip_bfloat16*)(ws + O_XBF);
    __hip_bfloat16* hc      = (__hip_bfloat16*)(ws + O_H);
    __hip_bfloat16* WqkvT   = (__hip_bfloat16*)(ws + O_WQKV);
    __hip_bfloat16* WoT     = (__hip_bfloat16*)(ws + O_WO);
    __hip_bfloat16* W1T     = (__hip_bfloat16*)(ws + O_W1);
    __hip_bfloat16* W2T     = (__hip_bfloat16*)(ws + O_W2);
    float*          bqkv    = (float*)(ws + O_BQKV);

    const dim3 blk(256);
    const float qscale = 0.17677669529663687f;

    // --- conversions (all tiled/coalesced) ---
    cvt_f2b<<<N_TOK * D_MODEL / 4 / 256, blk, 0, stream>>>(src, src_bf, N_TOK * D_MODEL);
    cvt_w3_tiled<<<dim3(24, 8), blk, 0, stream>>>(Wq, Wk, Wv, WqkvT, qscale);
    cvt_wt_tiled<<<dim3(8, 8),  blk, 0, stream>>>(Wo, WoT, 256, 256, 1.0f);
    cvt_wt_tiled<<<dim3(64, 8), blk, 0, stream>>>(W1, W1T, 256, DFF, 1.0f);
    cvt_wt_tiled<<<dim3(8, 64), blk, 0, stream>>>(W2, W2T, DFF, 256, 1.0f);
    make_bqkv<<<1, 768, 0, stream>>>(bq, bk, bv, bqkv, qscale);

    // --- fused QKV projection ---
    gemm_bt<<<dim3(6, 128), blk, 0, stream>>>(src_bf, 256, WqkvT, 256, bqkv,
                                              nullptr, nullptr, nullptr, qkv,
                                              N_TOK, 768, 256, 0, 0);
    // --- gathered attention ---
    attn_kernel<<<N_TOK, blk, 0, stream>>>(qkv, index_pair, kbc, ipb, attn_bf);

    // --- output projection + residual(src) -> y fp32 ---
    gemm_bt64<<<dim3(2, 256), blk, 0, stream>>>(attn_bf, 256, WoT, 256, bo,
                                                src, nullptr, yb, nullptr,
                                                N_TOK, 256, 256, 0, 0);
    // --- LN1 -> x bf16 ---
    ln_kernel<<<N_TOK, blk, 0, stream>>>(yb, g1, be1, nullptr, x_bf);

    // --- FFN ---
    for (int c = 0; c < DFF / ffc; ++c) {
        gemm_bt<<<dim3(ffc / 128, 128), blk, 0, stream>>>(
            x_bf, 256, W1T + (size_t)c * ffc * 256, 256,
            b1 + c * ffc, nullptr, nullptr, nullptr, hc,
            N_TOK, ffc, 256, 1 /*relu*/, 0);
        gemm_bt64<<<dim3(2, 256), blk, 0, stream>>>(
            hc, ffc, W2T + (size_t)c * ffc, DFF,
            (c == 0) ? b2 : nullptr, nullptr, (c == 0) ? x_bf : nullptr,
            zb, nullptr, N_TOK, 256, ffc, 0, (c > 0) ? 1 : 0);
    }

    // --- LN2 -> out ---
    ln_kernel<<<N_TOK, blk, 0, stream>>>(zb, g2, be2, out, nullptr);
}

// Round 4
// 223.778 us; speedup vs baseline: 4.5665x; 1.0333x over previous
//
#include <hip/hip_runtime.h>
#include <hip/hip_bf16.h>
#include <cstddef>
#include <cstdint>

#define D_MODEL 256
#define N_TOK   16384
#define NHEAD   8
#define HDIM    32
#define LNEIGH  32
#define DFF     2048

typedef short bf16x8 __attribute__((ext_vector_type(8)));
typedef float f32x4  __attribute__((ext_vector_type(4)));

__device__ __forceinline__ float b2f(short s) {
    unsigned u = ((unsigned)(unsigned short)s) << 16;
    return __builtin_bit_cast(float, u);
}

// global -> LDS async copy, 16B per lane; LDS fills base + lane*16.
__device__ __forceinline__ void gload_lds16(const void* g, void* l) {
    auto* gp = reinterpret_cast<const __attribute__((address_space(1))) uint32_t*>(
        reinterpret_cast<uintptr_t>(g));
    auto* lp = reinterpret_cast<__attribute__((address_space(3))) uint32_t*>(
        reinterpret_cast<uintptr_t>(l));
    __builtin_amdgcn_global_load_lds(gp, lp, 16, 0, 0);
}

// ---------------------------------------------------------------------------
// bf16 MFMA GEMM, 128x128 tile, 4 waves, double-buffered 2-phase K-loop.
// C = A[M,K] @ Bt[N,K]^T. Epilogue: +bias, +residf/+residb, relu, out f32/bf16.
// ---------------------------------------------------------------------------
__global__ __launch_bounds__(256) void gemm_bt(
    const __hip_bfloat16* __restrict__ A, int lda,
    const __hip_bfloat16* __restrict__ Bt, int ldb,
    const float* __restrict__ bias,
    const float* __restrict__ residf,
    const __hip_bfloat16* __restrict__ residb,
    float* __restrict__ outf,
    __hip_bfloat16* __restrict__ outb,
    int M, int N, int K, int relu, int accum)
{
    __shared__ short Asm[2][128 * 32];
    __shared__ short Bsm[2][128 * 32];

    const int tid  = threadIdx.x;
    const int lane = tid & 63;
    const int wid  = tid >> 6;
    const int wr   = wid >> 1;
    const int wc   = wid & 1;
    const int bm   = blockIdx.y * 128;
    const int bn   = blockIdx.x * 128;

    f32x4 acc[4][4] = {};
    const int srow = lane >> 2;
    const int seg  = (lane & 3) * 8;

    auto stage = [&](int buf, int k0) {
        #pragma unroll
        for (int t = 0; t < 2; ++t) {
            int rbase = wid * 32 + t * 16;
            gload_lds16(A  + (size_t)(bm + rbase + srow) * lda + k0 + seg, &Asm[buf][rbase * 32]);
            gload_lds16(Bt + (size_t)(bn + rbase + srow) * ldb + k0 + seg, &Bsm[buf][rbase * 32]);
        }
    };

    const int nk = K >> 5;
    stage(0, 0);
    __syncthreads();

    for (int kk = 0; kk < nk; ++kk) {
        const int cur = kk & 1;
        if (kk + 1 < nk) stage(cur ^ 1, (kk + 1) << 5);  // overlap with MFMA

        bf16x8 a[4], b[4];
        #pragma unroll
        for (int i = 0; i < 4; ++i)
            a[i] = *(const bf16x8*)&Asm[cur][(wr * 64 + i * 16 + (lane & 15)) * 32 + (lane >> 4) * 8];
        #pragma unroll
        for (int j = 0; j < 4; ++j)
            b[j] = *(const bf16x8*)&Bsm[cur][(wc * 64 + j * 16 + (lane & 15)) * 32 + (lane >> 4) * 8];
        #pragma unroll
        for (int i = 0; i < 4; ++i)
            #pragma unroll
            for (int j = 0; j < 4; ++j)
                acc[i][j] = __builtin_amdgcn_mfma_f32_16x16x32_bf16(a[i], b[j], acc[i][j], 0, 0, 0);
        __syncthreads();   // drains vmcnt for next buffer + protects reuse
    }

    #pragma unroll
    for (int i = 0; i < 4; ++i) {
        int rbase = bm + wr * 64 + i * 16 + ((lane >> 4) << 2);
        #pragma unroll
        for (int j = 0; j < 4; ++j) {
            int col = bn + wc * 64 + j * 16 + (lane & 15);
            float bval = bias ? bias[col] : 0.0f;
            #pragma unroll
            for (int r = 0; r < 4; ++r) {
                int row = rbase + r;
                float v = acc[i][j][r] + bval;
                size_t o = (size_t)row * N + col;
                if (residf) v += residf[o];
                if (residb) v += __bfloat162float(residb[o]);
                if (relu)   v = fmaxf(v, 0.0f);
                if (outf) { if (accum) outf[o] += v; else outf[o] = v; }
                if (outb) outb[o] = __float2bfloat16(v);
            }
        }
    }
}

// ---------------------------------------------------------------------------
// BM=64 x BN=128 variant (fallback path for N=256 GEMMs).
// ---------------------------------------------------------------------------
__global__ __launch_bounds__(256) void gemm_bt64(
    const __hip_bfloat16* __restrict__ A, int lda,
    const __hip_bfloat16* __restrict__ Bt, int ldb,
    const float* __restrict__ bias,
    const float* __restrict__ residf,
    const __hip_bfloat16* __restrict__ residb,
    float* __restrict__ outf,
    __hip_bfloat16* __restrict__ outb,
    int M, int N, int K, int relu, int accum)
{
    __shared__ short Asm[64 * 32];
    __shared__ short Bsm[128 * 32];

    const int tid  = threadIdx.x;
    const int lane = tid & 63;
    const int wid  = tid >> 6;
    const int wr   = wid >> 1;
    const int wc   = wid & 1;
    const int bm   = blockIdx.y * 64;
    const int bn   = blockIdx.x * 128;

    f32x4 acc[2][4] = {};
    const int srow = lane >> 2;
    const int seg  = (lane & 3) * 8;

    for (int k0 = 0; k0 < K; k0 += 32) {
        {
            int ra = wid * 16;
            gload_lds16(A + (size_t)(bm + ra + srow) * lda + k0 + seg, &Asm[ra * 32]);
        }
        #pragma unroll
        for (int t = 0; t < 2; ++t) {
            int rb = wid * 32 + t * 16;
            gload_lds16(Bt + (size_t)(bn + rb + srow) * ldb + k0 + seg, &Bsm[rb * 32]);
        }
        __syncthreads();

        bf16x8 a[2], b[4];
        #pragma unroll
        for (int i = 0; i < 2; ++i)
            a[i] = *(const bf16x8*)&Asm[(wr * 32 + i * 16 + (lane & 15)) * 32 + (lane >> 4) * 8];
        #pragma unroll
        for (int j = 0; j < 4; ++j)
            b[j] = *(const bf16x8*)&Bsm[(wc * 64 + j * 16 + (lane & 15)) * 32 + (lane >> 4) * 8];
        #pragma unroll
        for (int i = 0; i < 2; ++i)
            #pragma unroll
            for (int j = 0; j < 4; ++j)
                acc[i][j] = __builtin_amdgcn_mfma_f32_16x16x32_bf16(a[i], b[j], acc[i][j], 0, 0, 0);
        __syncthreads();
    }

    #pragma unroll
    for (int i = 0; i < 2; ++i) {
        int rbase = bm + wr * 32 + i * 16 + ((lane >> 4) << 2);
        #pragma unroll
        for (int j = 0; j < 4; ++j) {
            int col = bn + wc * 64 + j * 16 + (lane & 15);
            float bval = bias ? bias[col] : 0.0f;
            #pragma unroll
            for (int r = 0; r < 4; ++r) {
                int row = rbase + r;
                float v = acc[i][j][r] + bval;
                size_t o = (size_t)row * N + col;
                if (residf) v += residf[o];
                if (residb) v += __bfloat162float(residb[o]);
                if (relu)   v = fmaxf(v, 0.0f);
                if (outf) { if (accum) outf[o] += v; else outf[o] = v; }
                if (outb) outb[o] = __float2bfloat16(v);
            }
        }
    }
}

// ---------------------------------------------------------------------------
// BM=64 x BN=256 GEMM with fused bias + residual + LayerNorm epilogue.
// Each block owns 64 complete rows (N fixed = 256). Double-buffered K-loop.
// out = LN(A@Bt^T + bias + resid) * g + be   -> outf (f32) and/or outb (bf16)
// ---------------------------------------------------------------------------
__global__ __launch_bounds__(256) void gemm_bt_ln(
    const __hip_bfloat16* __restrict__ A, int lda,
    const __hip_bfloat16* __restrict__ Bt, int ldb,
    const float* __restrict__ bias,
    const float* __restrict__ residf,
    const __hip_bfloat16* __restrict__ residb,
    const float* __restrict__ g,
    const float* __restrict__ be,
    float* __restrict__ outf,
    __hip_bfloat16* __restrict__ outb,
    int K)
{
    __shared__ short Asm[2][64 * 32];
    __shared__ short Bsm[2][256 * 32];
    __shared__ float lnS[4][64], lnS2[4][64];
    __shared__ float rmu[64], rrs[64];

    const int tid  = threadIdx.x;
    const int lane = tid & 63;
    const int wid  = tid >> 6;           // wave owns cols [wid*64, wid*64+64)
    const int bm   = blockIdx.x * 64;
    const int lo   = lane & 15;
    const int hi   = lane >> 4;

    f32x4 acc[4][4] = {};
    const int srow = lane >> 2;
    const int seg  = (lane & 3) * 8;

    auto stage = [&](int buf, int k0) {
        {   // A: 64 rows x 32
            int ra = wid * 16;
            gload_lds16(A + (size_t)(bm + ra + srow) * lda + k0 + seg, &Asm[buf][ra * 32]);
        }
        #pragma unroll
        for (int t = 0; t < 4; ++t) {   // B: 256 rows x 32
            int rb = t * 64 + wid * 16;
            gload_lds16(Bt + (size_t)(rb + srow) * ldb + k0 + seg, &Bsm[buf][rb * 32]);
        }
    };

    const int nk = K >> 5;
    stage(0, 0);
    __syncthreads();

    for (int kk = 0; kk < nk; ++kk) {
        const int cur = kk & 1;
        if (kk + 1 < nk) stage(cur ^ 1, (kk + 1) << 5);

        bf16x8 a[4], b[4];
        #pragma unroll
        for (int i = 0; i < 4; ++i)
            a[i] = *(const bf16x8*)&Asm[cur][(i * 16 + lo) * 32 + hi * 8];
        #pragma unroll
        for (int j = 0; j < 4; ++j)
            b[j] = *(const bf16x8*)&Bsm[cur][(wid * 64 + j * 16 + lo) * 32 + hi * 8];
        #pragma unroll
        for (int i = 0; i < 4; ++i)
            #pragma unroll
            for (int j = 0; j < 4; ++j)
                acc[i][j] = __builtin_amdgcn_mfma_f32_16x16x32_bf16(a[i], b[j], acc[i][j], 0, 0, 0);
        __syncthreads();
    }

    // --- epilogue: v = acc + bias + resid; per-row mean/var; LN ---
    float ps[4][4] = {};    // [i][r] row partial sum (this wave's 64 cols)
    float ps2[4][4] = {};
    #pragma unroll
    for (int j = 0; j < 4; ++j) {
        int col = wid * 64 + j * 16 + lo;
        float bval = bias ? bias[col] : 0.0f;
        #pragma unroll
        for (int i = 0; i < 4; ++i) {
            #pragma unroll
            for (int r = 0; r < 4; ++r) {
                int row = bm + i * 16 + hi * 4 + r;
                float v = acc[i][j][r] + bval;
                size_t o = (size_t)row * 256 + col;
                if (residf) v += residf[o];
                if (residb) v += __bfloat162float(residb[o]);
                acc[i][j][r] = v;
                ps[i][r]  += v;
                ps2[i][r] += v * v;
            }
        }
    }
    // reduce across the 16 lanes sharing (hi, i, r)
    #pragma unroll
    for (int i = 0; i < 4; ++i)
        #pragma unroll
        for (int r = 0; r < 4; ++r) {
            #pragma unroll
            for (int m = 1; m < 16; m <<= 1) {
                ps[i][r]  += __shfl_xor(ps[i][r],  m);
                ps2[i][r] += __shfl_xor(ps2[i][r], m);
            }
        }
    if (lo == 0) {
        #pragma unroll
        for (int i = 0; i < 4; ++i)
            #pragma unroll
            for (int r = 0; r < 4; ++r) {
                int rl = i * 16 + hi * 4 + r;
                lnS[wid][rl]  = ps[i][r];
                lnS2[wid][rl] = ps2[i][r];
            }
    }
    __syncthreads();
    if (tid < 64) {
        float s  = lnS[0][tid] + lnS[1][tid] + lnS[2][tid] + lnS[3][tid];
        float s2 = lnS2[0][tid] + lnS2[1][tid] + lnS2[2][tid] + lnS2[3][tid];
        float mu  = s * (1.0f / 256.0f);
        float var = s2 * (1.0f / 256.0f) - mu * mu;
        rmu[tid] = mu;
        rrs[tid] = rsqrtf(var + 1e-5f);
    }
    __syncthreads();

    #pragma unroll
    for (int j = 0; j < 4; ++j) {
        int col = wid * 64 + j * 16 + lo;
        float gg = g[col], bb = be[col];
        #pragma unroll
        for (int i = 0; i < 4; ++i) {
            #pragma unroll
            for (int r = 0; r < 4; ++r) {
                int rl = i * 16 + hi * 4 + r;
                float v = (acc[i][j][r] - rmu[rl]) * rrs[rl] * gg + bb;
                size_t o = (size_t)(bm + rl) * 256 + col;
                if (outf) outf[o] = v;
                if (outb) outb[o] = __float2bfloat16(v);
            }
        }
    }
}

// ---------------------------------------------------------------------------
__global__ __launch_bounds__(256) void cvt_f2b(
    const float* __restrict__ x, __hip_bfloat16* __restrict__ y, int n)
{
    int i = (blockIdx.x * 256 + threadIdx.x) * 4;
    if (i >= n) return;
    float4 v = *(const float4*)(x + i);
    y[i + 0] = __float2bfloat16(v.x);
    y[i + 1] = __float2bfloat16(v.y);
    y[i + 2] = __float2bfloat16(v.z);
    y[i + 3] = __float2bfloat16(v.w);
}

// Tiled transpose: W[K][N] fp32 -> Wt[N][K] bf16.
__global__ __launch_bounds__(256) void cvt_wt_tiled(
    const float* __restrict__ W, __hip_bfloat16* __restrict__ Wt,
    int K, int N, float scale)
{
    __shared__ float t[32][33];
    const int n0 = blockIdx.x * 32;
    const int k0 = blockIdx.y * 32;
    const int tx = threadIdx.x & 31;
    const int ty = threadIdx.x >> 5;
    #pragma unroll
    for (int i = 0; i < 32; i += 8)
        t[ty + i][tx] = W[(size_t)(k0 + ty + i) * N + n0 + tx];
    __syncthreads();
    #pragma unroll
    for (int i = 0; i < 32; i += 8)
        Wt[(size_t)(n0 + ty + i) * K + k0 + tx] = __float2bfloat16(t[tx][ty + i] * scale);
}

// Fused Wq/Wk/Wv transpose into WqkvT[768][256]; q columns pre-scaled.
__global__ __launch_bounds__(256) void cvt_w3_tiled(
    const float* __restrict__ Wa, const float* __restrict__ Wb,
    const float* __restrict__ Wc, __hip_bfloat16* __restrict__ Wt,
    float scale_a)
{
    __shared__ float t[32][33];
    const int n0 = blockIdx.x * 32;
    const int k0 = blockIdx.y * 32;
    const float* W = (n0 < 256) ? Wa : (n0 < 512 ? Wb : Wc);
    const float sc = (n0 < 256) ? scale_a : 1.0f;
    const int ncol = n0 & 255;
    const int tx = threadIdx.x & 31;
    const int ty = threadIdx.x >> 5;
    #pragma unroll
    for (int i = 0; i < 32; i += 8)
        t[ty + i][tx] = W[(size_t)(k0 + ty + i) * 256 + ncol + tx];
    __syncthreads();
    #pragma unroll
    for (int i = 0; i < 32; i += 8)
        Wt[(size_t)(n0 + ty + i) * 256 + k0 + tx] = __float2bfloat16(t[tx][ty + i] * sc);
}

__global__ __launch_bounds__(768) void make_bqkv(
    const float* __restrict__ bq, const float* __restrict__ bk,
    const float* __restrict__ bv, float* __restrict__ o, float qs)
{
    int i = threadIdx.x;
    if (i < 256)      o[i] = bq[i] * qs;
    else if (i < 512) o[i] = bk[i - 256];
    else              o[i] = bv[i - 512];
}

// ---------------------------------------------------------------------------
// Gathered local attention, bf16 qkv[N][768]. One block per query.
// ---------------------------------------------------------------------------
__global__ __launch_bounds__(256) void attn_kernel(
    const __hip_bfloat16* __restrict__ qkv,
    const int* __restrict__ index_pair,
    const int* __restrict__ key_batch_cnt,
    const int* __restrict__ ipb,
    __hip_bfloat16* __restrict__ out)
{
    const int blk = blockIdx.x;
    const int n   = (blk & 7) * 2048 + (blk >> 3);   // XCD swizzle
    const int tid = threadIdx.x;

    __shared__ float qs[256];
    __shared__ float wsm[256];
    __shared__ int   gidx[32];

    if (tid < 32) {
        int raw = index_pair[(size_t)n * LNEIGH + tid];
        int b = ipb[n];
        int off = 0;
        for (int i = 0; i < b; ++i) off += key_batch_cnt[i];
        gidx[tid] = (raw >= 0) ? (raw + off) : -1;
    }
    qs[tid] = __bfloat162float(qkv[(size_t)n * 768 + tid]);
    __syncthreads();

    const int h = tid >> 5;
    const int l = tid & 31;
    int gi = gidx[l];
    float logit = -1e9f;
    if (gi >= 0) {
        const bf16x8* kp = (const bf16x8*)(qkv + (size_t)gi * 768 + 256 + h * HDIM);
        float s = 0.0f;
        #pragma unroll
        for (int u = 0; u < 4; ++u) {
            bf16x8 kv8 = kp[u];
            #pragma unroll
            for (int j = 0; j < 8; ++j)
                s += qs[h * HDIM + u * 8 + j] * b2f(kv8[j]);
        }
        logit = s;
    }
    float mx = logit;
    #pragma unroll
    for (int o = 16; o >= 1; o >>= 1) mx = fmaxf(mx, __shfl_xor(mx, o));
    float p = expf(logit - mx);
    float ssum = p;
    #pragma unroll
    for (int o = 16; o >= 1; o >>= 1) ssum += __shfl_xor(ssum, o);
    wsm[tid] = p / ssum;
    __syncthreads();

    const int d  = tid;
    const int h2 = d >> 5;
    float o = 0.0f;
    #pragma unroll 8
    for (int l2 = 0; l2 < LNEIGH; ++l2) {
        int gi2 = gidx[l2];
        if (gi2 < 0) gi2 = 0;
        o += wsm[(h2 << 5) | l2] * __bfloat162float(qkv[(size_t)gi2 * 768 + 512 + d]);
    }
    out[(size_t)n * D_MODEL + d] = __float2bfloat16(o);
}

// ---------------------------------------------------------------------------
// LayerNorm rows of 256 (fallback path only).
// ---------------------------------------------------------------------------
__global__ __launch_bounds__(256) void ln_kernel(
    const float* __restrict__ x,
    const float* __restrict__ g,
    const float* __restrict__ b,
    float* __restrict__ outf,
    __hip_bfloat16* __restrict__ outb)
{
    const int row = blockIdx.x;
    const int tid = threadIdx.x;
    float val = x[(size_t)row * D_MODEL + tid];
    float s = val, s2 = val * val;
    #pragma unroll
    for (int o = 32; o >= 1; o >>= 1) {
        s  += __shfl_xor(s,  o);
        s2 += __shfl_xor(s2, o);
    }
    __shared__ float ss[4], ss2[4];
    const int wid = tid >> 6;
    if ((tid & 63) == 0) { ss[wid] = s; ss2[wid] = s2; }
    __syncthreads();
    s  = ss[0] + ss[1] + ss[2] + ss[3];
    s2 = ss2[0] + ss2[1] + ss2[2] + ss2[3];
    float mu  = s * (1.0f / D_MODEL);
    float var = s2 * (1.0f / D_MODEL) - mu * mu;
    float inv = rsqrtf(var + 1e-5f);
    float r = (val - mu) * inv * g[tid] + b[tid];
    if (outf) outf[(size_t)row * D_MODEL + tid] = r;
    if (outb) outb[(size_t)row * D_MODEL + tid] = __float2bfloat16(r);
}

// ---------------------------------------------------------------------------
extern "C" void kernel_launch(void* const* d_in, const int* in_sizes, int n_in,
                              void* d_out, int out_size, void* d_ws, size_t ws_size,
                              hipStream_t stream)
{
    const float* src = (const float*)d_in[0];
    const int*   index_pair = (const int*)d_in[1];
    const int*   kbc = (const int*)d_in[3];
    const int*   ipb = (const int*)d_in[4];
    const float* Wq = (const float*)d_in[5];
    const float* bq = (const float*)d_in[6];
    const float* Wk = (const float*)d_in[7];
    const float* bk = (const float*)d_in[8];
    const float* Wv = (const float*)d_in[9];
    const float* bv = (const float*)d_in[10];
    const float* Wo = (const float*)d_in[11];
    const float* bo = (const float*)d_in[12];
    const float* W1 = (const float*)d_in[13];
    const float* b1 = (const float*)d_in[14];
    const float* W2 = (const float*)d_in[15];
    const float* b2 = (const float*)d_in[16];
    const float* g1 = (const float*)d_in[17];
    const float* be1 = (const float*)d_in[18];
    const float* g2 = (const float*)d_in[19];
    const float* be2 = (const float*)d_in[20];
    float* out = (float*)d_out;

    char* ws = (char*)d_ws;
    const size_t O_SRCBF = 0;                        // 8.39 MB (reused: attn_bf)
    const size_t O_QKV   = 8388608;                  // 25.17 MB
    const size_t O_XBF   = 33554432;                 // 8.39 MB
    const size_t O_WQKV  = 41943040;                 // 0.39 MB
    const size_t O_WO    = O_WQKV + 768 * 256 * 2;
    const size_t O_W1    = O_WO + 256 * 256 * 2;
    const size_t O_W2    = O_W1 + (size_t)DFF * 256 * 2;
    const size_t O_BQKV  = O_W2 + (size_t)DFF * 256 * 2;
    const size_t O_H     = O_BQKV + 4096;            // hidden buffer

    __hip_bfloat16* src_bf  = (__hip_bfloat16*)(ws + O_SRCBF);
    __hip_bfloat16* attn_bf = (__hip_bfloat16*)(ws + O_SRCBF);
    __hip_bfloat16* qkv     = (__hip_bfloat16*)(ws + O_QKV);
    __hip_bfloat16* x_bf    = (__hip_bfloat16*)(ws + O_XBF);
    __hip_bfloat16* WqkvT   = (__hip_bfloat16*)(ws + O_WQKV);
    __hip_bfloat16* WoT     = (__hip_bfloat16*)(ws + O_WO);
    __hip_bfloat16* W1T     = (__hip_bfloat16*)(ws + O_W1);
    __hip_bfloat16* W2T     = (__hip_bfloat16*)(ws + O_W2);
    float*          bqkv    = (float*)(ws + O_BQKV);
    __hip_bfloat16* hc      = (__hip_bfloat16*)(ws + O_H);

    const bool fused_ffn = ws_size >= O_H + (size_t)N_TOK * DFF * 2;

    const dim3 blk(256);
    const float qscale = 0.17677669529663687f;

    // --- conversions ---
    cvt_f2b<<<N_TOK * D_MODEL / 4 / 256, blk, 0, stream>>>(src, src_bf, N_TOK * D_MODEL);
    cvt_w3_tiled<<<dim3(24, 8), blk, 0, stream>>>(Wq, Wk, Wv, WqkvT, qscale);
    cvt_wt_tiled<<<dim3(8, 8),  blk, 0, stream>>>(Wo, WoT, 256, 256, 1.0f);
    cvt_wt_tiled<<<dim3(64, 8), blk, 0, stream>>>(W1, W1T, 256, DFF, 1.0f);
    cvt_wt_tiled<<<dim3(8, 64), blk, 0, stream>>>(W2, W2T, DFF, 256, 1.0f);
    make_bqkv<<<1, 768, 0, stream>>>(bq, bk, bv, bqkv, qscale);

    // --- fused QKV projection ---
    gemm_bt<<<dim3(6, 128), blk, 0, stream>>>(src_bf, 256, WqkvT, 256, bqkv,
                                              nullptr, nullptr, nullptr, qkv,
                                              N_TOK, 768, 256, 0, 0);
    // --- gathered attention ---
    attn_kernel<<<N_TOK, blk, 0, stream>>>(qkv, index_pair, kbc, ipb, attn_bf);

    // --- Wo + residual(src) + LN1 fused -> x_bf ---
    gemm_bt_ln<<<dim3(N_TOK / 64), blk, 0, stream>>>(
        attn_bf, 256, WoT, 256, bo, src, nullptr, g1, be1,
        nullptr, x_bf, 256);

    if (fused_ffn) {
        // --- FFN1 (single dispatch, N=2048, relu) ---
        gemm_bt<<<dim3(16, 128), blk, 0, stream>>>(
            x_bf, 256, W1T, 256, b1, nullptr, nullptr, nullptr, hc,
            N_TOK, DFF, 256, 1, 0);
        // --- FFN2 + residual(x_bf) + LN2 fused -> out ---
        gemm_bt_ln<<<dim3(N_TOK / 64), blk, 0, stream>>>(
            hc, DFF, W2T, DFF, b2, nullptr, x_bf, g2, be2,
            out, nullptr, DFF);
    } else {
        // fallback: chunked FFN + separate LN2
        float* zb = (float*)(ws + O_H + (size_t)N_TOK * 512 * 2);
        const int ffc = 512;
        for (int c = 0; c < DFF / ffc; ++c) {
            gemm_bt<<<dim3(ffc / 128, 128), blk, 0, stream>>>(
                x_bf, 256, W1T + (size_t)c * ffc * 256, 256,
                b1 + c * ffc, nullptr, nullptr, nullptr, hc,
                N_TOK, ffc, 256, 1, 0);
            gemm_bt64<<<dim3(2, 256), blk, 0, stream>>>(
                hc, ffc, W2T + (size_t)c * ffc, DFF,
                (c == 0) ? b2 : nullptr, nullptr, (c == 0) ? x_bf : nullptr,
                zb, nullptr, N_TOK, 256, ffc, 0, (c > 0) ? 1 : 0);
        }
        ln_kernel<<<N_TOK, blk, 0, stream>>>(zb, g2, be2, out, nullptr);
    }
}

// Round 5
// 203.352 us; speedup vs baseline: 5.0252x; 1.1004x over previous
//
#include <hip/hip_runtime.h>
#include <hip/hip_bf16.h>
#include <cstddef>
#include <cstdint>

#define D_MODEL 256
#define N_TOK   16384
#define NHEAD   8
#define HDIM    32
#define LNEIGH  32
#define DFF     2048

typedef short bf16x8 __attribute__((ext_vector_type(8)));
typedef float f32x4  __attribute__((ext_vector_type(4)));

__device__ __forceinline__ float b2f(short s) {
    unsigned u = ((unsigned)(unsigned short)s) << 16;
    return __builtin_bit_cast(float, u);
}

// global -> LDS async copy, 16B per lane; LDS fills base + lane*16.
__device__ __forceinline__ void gload_lds16(const void* g, void* l) {
    auto* gp = reinterpret_cast<const __attribute__((address_space(1))) uint32_t*>(
        reinterpret_cast<uintptr_t>(g));
    auto* lp = reinterpret_cast<__attribute__((address_space(3))) uint32_t*>(
        reinterpret_cast<uintptr_t>(l));
    __builtin_amdgcn_global_load_lds(gp, lp, 16, 0, 0);
}

// ---------------------------------------------------------------------------
// bf16 MFMA GEMM, 128x128 tile, 4 waves, double-buffered 2-phase K-loop.
// C = A[M,K] @ Bt[N,K]^T. Epilogue: +bias, +residf/+residb, relu, out f32/bf16.
// ---------------------------------------------------------------------------
__global__ __launch_bounds__(256) void gemm_bt(
    const __hip_bfloat16* __restrict__ A, int lda,
    const __hip_bfloat16* __restrict__ Bt, int ldb,
    const float* __restrict__ bias,
    const float* __restrict__ residf,
    const __hip_bfloat16* __restrict__ residb,
    float* __restrict__ outf,
    __hip_bfloat16* __restrict__ outb,
    int M, int N, int K, int relu, int accum)
{
    __shared__ short Asm[2][128 * 32];
    __shared__ short Bsm[2][128 * 32];

    const int tid  = threadIdx.x;
    const int lane = tid & 63;
    const int wid  = tid >> 6;
    const int wr   = wid >> 1;
    const int wc   = wid & 1;
    const int bm   = blockIdx.y * 128;
    const int bn   = blockIdx.x * 128;

    f32x4 acc[4][4] = {};
    const int srow = lane >> 2;
    const int seg  = (lane & 3) * 8;

    auto stage = [&](int buf, int k0) {
        #pragma unroll
        for (int t = 0; t < 2; ++t) {
            int rbase = wid * 32 + t * 16;
            gload_lds16(A  + (size_t)(bm + rbase + srow) * lda + k0 + seg, &Asm[buf][rbase * 32]);
            gload_lds16(Bt + (size_t)(bn + rbase + srow) * ldb + k0 + seg, &Bsm[buf][rbase * 32]);
        }
    };

    const int nk = K >> 5;
    stage(0, 0);
    __syncthreads();

    for (int kk = 0; kk < nk; ++kk) {
        const int cur = kk & 1;
        if (kk + 1 < nk) stage(cur ^ 1, (kk + 1) << 5);

        bf16x8 a[4], b[4];
        #pragma unroll
        for (int i = 0; i < 4; ++i)
            a[i] = *(const bf16x8*)&Asm[cur][(wr * 64 + i * 16 + (lane & 15)) * 32 + (lane >> 4) * 8];
        #pragma unroll
        for (int j = 0; j < 4; ++j)
            b[j] = *(const bf16x8*)&Bsm[cur][(wc * 64 + j * 16 + (lane & 15)) * 32 + (lane >> 4) * 8];
        #pragma unroll
        for (int i = 0; i < 4; ++i)
            #pragma unroll
            for (int j = 0; j < 4; ++j)
                acc[i][j] = __builtin_amdgcn_mfma_f32_16x16x32_bf16(a[i], b[j], acc[i][j], 0, 0, 0);
        __syncthreads();
    }

    #pragma unroll
    for (int i = 0; i < 4; ++i) {
        int rbase = bm + wr * 64 + i * 16 + ((lane >> 4) << 2);
        #pragma unroll
        for (int j = 0; j < 4; ++j) {
            int col = bn + wc * 64 + j * 16 + (lane & 15);
            float bval = bias ? bias[col] : 0.0f;
            #pragma unroll
            for (int r = 0; r < 4; ++r) {
                int row = rbase + r;
                float v = acc[i][j][r] + bval;
                size_t o = (size_t)row * N + col;
                if (residf) v += residf[o];
                if (residb) v += __bfloat162float(residb[o]);
                if (relu)   v = fmaxf(v, 0.0f);
                if (outf) { if (accum) outf[o] += v; else outf[o] = v; }
                if (outb) outb[o] = __float2bfloat16(v);
            }
        }
    }
}

// ---------------------------------------------------------------------------
// BM=64 x BN=128 variant (fallback path only).
// ---------------------------------------------------------------------------
__global__ __launch_bounds__(256) void gemm_bt64(
    const __hip_bfloat16* __restrict__ A, int lda,
    const __hip_bfloat16* __restrict__ Bt, int ldb,
    const float* __restrict__ bias,
    const float* __restrict__ residf,
    const __hip_bfloat16* __restrict__ residb,
    float* __restrict__ outf,
    __hip_bfloat16* __restrict__ outb,
    int M, int N, int K, int relu, int accum)
{
    __shared__ short Asm[64 * 32];
    __shared__ short Bsm[128 * 32];

    const int tid  = threadIdx.x;
    const int lane = tid & 63;
    const int wid  = tid >> 6;
    const int wr   = wid >> 1;
    const int wc   = wid & 1;
    const int bm   = blockIdx.y * 64;
    const int bn   = blockIdx.x * 128;

    f32x4 acc[2][4] = {};
    const int srow = lane >> 2;
    const int seg  = (lane & 3) * 8;

    for (int k0 = 0; k0 < K; k0 += 32) {
        {
            int ra = wid * 16;
            gload_lds16(A + (size_t)(bm + ra + srow) * lda + k0 + seg, &Asm[ra * 32]);
        }
        #pragma unroll
        for (int t = 0; t < 2; ++t) {
            int rb = wid * 32 + t * 16;
            gload_lds16(Bt + (size_t)(bn + rb + srow) * ldb + k0 + seg, &Bsm[rb * 32]);
        }
        __syncthreads();

        bf16x8 a[2], b[4];
        #pragma unroll
        for (int i = 0; i < 2; ++i)
            a[i] = *(const bf16x8*)&Asm[(wr * 32 + i * 16 + (lane & 15)) * 32 + (lane >> 4) * 8];
        #pragma unroll
        for (int j = 0; j < 4; ++j)
            b[j] = *(const bf16x8*)&Bsm[(wc * 64 + j * 16 + (lane & 15)) * 32 + (lane >> 4) * 8];
        #pragma unroll
        for (int i = 0; i < 2; ++i)
            #pragma unroll
            for (int j = 0; j < 4; ++j)
                acc[i][j] = __builtin_amdgcn_mfma_f32_16x16x32_bf16(a[i], b[j], acc[i][j], 0, 0, 0);
        __syncthreads();
    }

    #pragma unroll
    for (int i = 0; i < 2; ++i) {
        int rbase = bm + wr * 32 + i * 16 + ((lane >> 4) << 2);
        #pragma unroll
        for (int j = 0; j < 4; ++j) {
            int col = bn + wc * 64 + j * 16 + (lane & 15);
            float bval = bias ? bias[col] : 0.0f;
            #pragma unroll
            for (int r = 0; r < 4; ++r) {
                int row = rbase + r;
                float v = acc[i][j][r] + bval;
                size_t o = (size_t)row * N + col;
                if (residf) v += residf[o];
                if (residb) v += __bfloat162float(residb[o]);
                if (relu)   v = fmaxf(v, 0.0f);
                if (outf) { if (accum) outf[o] += v; else outf[o] = v; }
                if (outb) outb[o] = __float2bfloat16(v);
            }
        }
    }
}

// ---------------------------------------------------------------------------
// 8-wave BM=64 x BN=256 GEMM + fused bias/residual/LayerNorm epilogue.
// 512 threads: wave (wr=wid>>2, wc=wid&3) owns rows [wr*32,+32) x cols [wc*64,+64).
// Grid = M/64 blocks -> 8 waves/CU at grid 256 (vs 4 for the 4-wave version).
// ---------------------------------------------------------------------------
__global__ __launch_bounds__(512) void gemm_bt_ln8(
    const __hip_bfloat16* __restrict__ A, int lda,
    const __hip_bfloat16* __restrict__ Bt, int ldb,
    const float* __restrict__ bias,
    const float* __restrict__ residf,
    const __hip_bfloat16* __restrict__ residb,
    const float* __restrict__ g,
    const float* __restrict__ be,
    float* __restrict__ outf,
    __hip_bfloat16* __restrict__ outb,
    int K)
{
    __shared__ short Asm[2][64 * 32];
    __shared__ short Bsm[2][256 * 32];
    __shared__ float lnS[8][64], lnS2[8][64];
    __shared__ float rmu[64], rrs[64];

    const int tid  = threadIdx.x;
    const int lane = tid & 63;
    const int wid  = tid >> 6;           // 0..7
    const int wr   = wid >> 2;           // 0..1
    const int wc   = wid & 3;            // 0..3
    const int bm   = blockIdx.x * 64;
    const int lo   = lane & 15;
    const int hi   = lane >> 4;

    f32x4 acc[2][4] = {};
    const int srow = lane >> 2;
    const int seg  = (lane & 3) * 8;

    auto stage = [&](int buf, int k0) {
        if (wid < 4) {                   // A: 64 rows, 4 stripes
            int ra = wid * 16;
            gload_lds16(A + (size_t)(bm + ra + srow) * lda + k0 + seg, &Asm[buf][ra * 32]);
        }
        #pragma unroll
        for (int t = 0; t < 2; ++t) {    // B: 256 rows, 16 stripes over 8 waves
            int rb = wid * 32 + t * 16;
            gload_lds16(Bt + (size_t)(rb + srow) * ldb + k0 + seg, &Bsm[buf][rb * 32]);
        }
    };

    const int nk = K >> 5;
    stage(0, 0);
    __syncthreads();

    for (int kk = 0; kk < nk; ++kk) {
        const int cur = kk & 1;
        if (kk + 1 < nk) stage(cur ^ 1, (kk + 1) << 5);

        bf16x8 a[2], b[4];
        #pragma unroll
        for (int i = 0; i < 2; ++i)
            a[i] = *(const bf16x8*)&Asm[cur][(wr * 32 + i * 16 + lo) * 32 + hi * 8];
        #pragma unroll
        for (int j = 0; j < 4; ++j)
            b[j] = *(const bf16x8*)&Bsm[cur][(wc * 64 + j * 16 + lo) * 32 + hi * 8];
        #pragma unroll
        for (int i = 0; i < 2; ++i)
            #pragma unroll
            for (int j = 0; j < 4; ++j)
                acc[i][j] = __builtin_amdgcn_mfma_f32_16x16x32_bf16(a[i], b[j], acc[i][j], 0, 0, 0);
        __syncthreads();
    }

    // epilogue: bias + resid, per-row mean/var partials
    float ps[2][4] = {}, ps2[2][4] = {};
    #pragma unroll
    for (int j = 0; j < 4; ++j) {
        int col = wc * 64 + j * 16 + lo;
        float bval = bias ? bias[col] : 0.0f;
        #pragma unroll
        for (int i = 0; i < 2; ++i) {
            #pragma unroll
            for (int r = 0; r < 4; ++r) {
                int row = bm + wr * 32 + i * 16 + hi * 4 + r;
                float v = acc[i][j][r] + bval;
                size_t o = (size_t)row * 256 + col;
                if (residf) v += residf[o];
                if (residb) v += __bfloat162float(residb[o]);
                acc[i][j][r] = v;
                ps[i][r]  += v;
                ps2[i][r] += v * v;
            }
        }
    }
    #pragma unroll
    for (int i = 0; i < 2; ++i)
        #pragma unroll
        for (int r = 0; r < 4; ++r) {
            #pragma unroll
            for (int m = 1; m < 16; m <<= 1) {
                ps[i][r]  += __shfl_xor(ps[i][r],  m);
                ps2[i][r] += __shfl_xor(ps2[i][r], m);
            }
        }
    if (lo == 0) {
        #pragma unroll
        for (int i = 0; i < 2; ++i)
            #pragma unroll
            for (int r = 0; r < 4; ++r) {
                int rl = wr * 32 + i * 16 + hi * 4 + r;
                lnS[wid][rl]  = ps[i][r];
                lnS2[wid][rl] = ps2[i][r];
            }
    }
    __syncthreads();
    if (tid < 64) {
        int base = (tid >> 5) * 4;       // wave ids sharing this row
        float s  = lnS[base][tid] + lnS[base + 1][tid] + lnS[base + 2][tid] + lnS[base + 3][tid];
        float s2 = lnS2[base][tid] + lnS2[base + 1][tid] + lnS2[base + 2][tid] + lnS2[base + 3][tid];
        float mu  = s * (1.0f / 256.0f);
        float var = s2 * (1.0f / 256.0f) - mu * mu;
        rmu[tid] = mu;
        rrs[tid] = rsqrtf(var + 1e-5f);
    }
    __syncthreads();

    #pragma unroll
    for (int j = 0; j < 4; ++j) {
        int col = wc * 64 + j * 16 + lo;
        float gg = g[col], bb = be[col];
        #pragma unroll
        for (int i = 0; i < 2; ++i) {
            #pragma unroll
            for (int r = 0; r < 4; ++r) {
                int rl = wr * 32 + i * 16 + hi * 4 + r;
                float v = (acc[i][j][r] - rmu[rl]) * rrs[rl] * gg + bb;
                size_t o = (size_t)(bm + rl) * 256 + col;
                if (outf) outf[o] = v;
                if (outb) outb[o] = __float2bfloat16(v);
            }
        }
    }
}

// ---------------------------------------------------------------------------
__global__ __launch_bounds__(256) void cvt_f2b(
    const float* __restrict__ x, __hip_bfloat16* __restrict__ y, int n)
{
    int i = (blockIdx.x * 256 + threadIdx.x) * 4;
    if (i >= n) return;
    float4 v = *(const float4*)(x + i);
    y[i + 0] = __float2bfloat16(v.x);
    y[i + 1] = __float2bfloat16(v.y);
    y[i + 2] = __float2bfloat16(v.z);
    y[i + 3] = __float2bfloat16(v.w);
}

// Tiled transpose: W[K][N] fp32 -> Wt[N][K] bf16.
__global__ __launch_bounds__(256) void cvt_wt_tiled(
    const float* __restrict__ W, __hip_bfloat16* __restrict__ Wt,
    int K, int N, float scale)
{
    __shared__ float t[32][33];
    const int n0 = blockIdx.x * 32;
    const int k0 = blockIdx.y * 32;
    const int tx = threadIdx.x & 31;
    const int ty = threadIdx.x >> 5;
    #pragma unroll
    for (int i = 0; i < 32; i += 8)
        t[ty + i][tx] = W[(size_t)(k0 + ty + i) * N + n0 + tx];
    __syncthreads();
    #pragma unroll
    for (int i = 0; i < 32; i += 8)
        Wt[(size_t)(n0 + ty + i) * K + k0 + tx] = __float2bfloat16(t[tx][ty + i] * scale);
}

// Fused Wq/Wk/Wv transpose into WqkvT[768][256]; q columns pre-scaled.
__global__ __launch_bounds__(256) void cvt_w3_tiled(
    const float* __restrict__ Wa, const float* __restrict__ Wb,
    const float* __restrict__ Wc, __hip_bfloat16* __restrict__ Wt,
    float scale_a)
{
    __shared__ float t[32][33];
    const int n0 = blockIdx.x * 32;
    const int k0 = blockIdx.y * 32;
    const float* W = (n0 < 256) ? Wa : (n0 < 512 ? Wb : Wc);
    const float sc = (n0 < 256) ? scale_a : 1.0f;
    const int ncol = n0 & 255;
    const int tx = threadIdx.x & 31;
    const int ty = threadIdx.x >> 5;
    #pragma unroll
    for (int i = 0; i < 32; i += 8)
        t[ty + i][tx] = W[(size_t)(k0 + ty + i) * 256 + ncol + tx];
    __syncthreads();
    #pragma unroll
    for (int i = 0; i < 32; i += 8)
        Wt[(size_t)(n0 + ty + i) * 256 + k0 + tx] = __float2bfloat16(t[tx][ty + i] * sc);
}

__global__ __launch_bounds__(768) void make_bqkv(
    const float* __restrict__ bq, const float* __restrict__ bk,
    const float* __restrict__ bv, float* __restrict__ o, float qs)
{
    int i = threadIdx.x;
    if (i < 256)      o[i] = bq[i] * qs;
    else if (i < 512) o[i] = bk[i - 256];
    else              o[i] = bv[i - 512];
}

// ---------------------------------------------------------------------------
// Gathered local attention, bf16 qkv[N][768]. One block (256 thr) per query.
// QK: thread (h,l), q read from global (L1-broadcast), k gathered 16B/lane.
// PV: 8 groups x 32 threads, 16B v loads, LDS partial reduce.
// ---------------------------------------------------------------------------
__global__ __launch_bounds__(256) void attn_kernel(
    const __hip_bfloat16* __restrict__ qkv,
    const int* __restrict__ index_pair,
    const int* __restrict__ key_batch_cnt,
    const int* __restrict__ ipb,
    __hip_bfloat16* __restrict__ out)
{
    const int blk = blockIdx.x;
    const int n   = (blk & 7) * 2048 + (blk >> 3);   // XCD swizzle
    const int tid = threadIdx.x;

    __shared__ float wsm[256];       // attn weights [h][l]
    __shared__ float pos[8][256];    // PV partials per l-group
    __shared__ int   gidx[32];

    if (tid < 32) {
        int raw = index_pair[(size_t)n * LNEIGH + tid];
        int b = ipb[n];
        int off = 0;
        for (int i = 0; i < b; ++i) off += key_batch_cnt[i];
        gidx[tid] = (raw >= 0) ? (raw + off) : -1;
    }
    __syncthreads();

    const int h = tid >> 5;
    const int l = tid & 31;
    {
        int gi = gidx[l];
        float s = -1e9f;
        if (gi >= 0) {
            const bf16x8* kp = (const bf16x8*)(qkv + (size_t)gi * 768 + 256 + h * HDIM);
            const bf16x8* qp = (const bf16x8*)(qkv + (size_t)n  * 768 +       h * HDIM);
            s = 0.0f;
            #pragma unroll
            for (int u = 0; u < 4; ++u) {
                bf16x8 kv8 = kp[u];
                bf16x8 qv8 = qp[u];
                #pragma unroll
                for (int j = 0; j < 8; ++j)
                    s += b2f(qv8[j]) * b2f(kv8[j]);
            }
        }
        float mx = s;
        #pragma unroll
        for (int o = 16; o >= 1; o >>= 1) mx = fmaxf(mx, __shfl_xor(mx, o));
        float p = expf(s - mx);
        float ss = p;
        #pragma unroll
        for (int o = 16; o >= 1; o >>= 1) ss += __shfl_xor(ss, o);
        wsm[tid] = p / ss;
    }
    __syncthreads();

    // PV: group g handles l in {g, g+8, g+16, g+24}; thread t covers d=t*8..t*8+7
    const int gr = tid >> 5;
    const int t  = tid & 31;
    float a8[8] = {};
    #pragma unroll
    for (int i = 0; i < 4; ++i) {
        int l2 = gr + i * 8;
        int gi = gidx[l2];
        if (gi < 0) gi = 0;                       // ref gathers row 0 when invalid
        float w = wsm[((t >> 2) << 5) | l2];      // head = (t*8)>>5 = t>>2
        bf16x8 vv = *(const bf16x8*)(qkv + (size_t)gi * 768 + 512 + t * 8);
        #pragma unroll
        for (int j = 0; j < 8; ++j) a8[j] += w * b2f(vv[j]);
    }
    #pragma unroll
    for (int j = 0; j < 8; ++j) pos[gr][t * 8 + j] = a8[j];
    __syncthreads();

    float o = 0.0f;
    #pragma unroll
    for (int gg = 0; gg < 8; ++gg) o += pos[gg][tid];
    out[(size_t)n * D_MODEL + tid] = __float2bfloat16(o);
}

// ---------------------------------------------------------------------------
// LayerNorm rows of 256 (fallback path only).
// ---------------------------------------------------------------------------
__global__ __launch_bounds__(256) void ln_kernel(
    const float* __restrict__ x,
    const float* __restrict__ g,
    const float* __restrict__ b,
    float* __restrict__ outf,
    __hip_bfloat16* __restrict__ outb)
{
    const int row = blockIdx.x;
    const int tid = threadIdx.x;
    float val = x[(size_t)row * D_MODEL + tid];
    float s = val, s2 = val * val;
    #pragma unroll
    for (int o = 32; o >= 1; o >>= 1) {
        s  += __shfl_xor(s,  o);
        s2 += __shfl_xor(s2, o);
    }
    __shared__ float ss[4], ss2[4];
    const int wid = tid >> 6;
    if ((tid & 63) == 0) { ss[wid] = s; ss2[wid] = s2; }
    __syncthreads();
    s  = ss[0] + ss[1] + ss[2] + ss[3];
    s2 = ss2[0] + ss2[1] + ss2[2] + ss2[3];
    float mu  = s * (1.0f / D_MODEL);
    float var = s2 * (1.0f / D_MODEL) - mu * mu;
    float inv = rsqrtf(var + 1e-5f);
    float r = (val - mu) * inv * g[tid] + b[tid];
    if (outf) outf[(size_t)row * D_MODEL + tid] = r;
    if (outb) outb[(size_t)row * D_MODEL + tid] = __float2bfloat16(r);
}

// ---------------------------------------------------------------------------
extern "C" void kernel_launch(void* const* d_in, const int* in_sizes, int n_in,
                              void* d_out, int out_size, void* d_ws, size_t ws_size,
                              hipStream_t stream)
{
    const float* src = (const float*)d_in[0];
    const int*   index_pair = (const int*)d_in[1];
    const int*   kbc = (const int*)d_in[3];
    const int*   ipb = (const int*)d_in[4];
    const float* Wq = (const float*)d_in[5];
    const float* bq = (const float*)d_in[6];
    const float* Wk = (const float*)d_in[7];
    const float* bk = (const float*)d_in[8];
    const float* Wv = (const float*)d_in[9];
    const float* bv = (const float*)d_in[10];
    const float* Wo = (const float*)d_in[11];
    const float* bo = (const float*)d_in[12];
    const float* W1 = (const float*)d_in[13];
    const float* b1 = (const float*)d_in[14];
    const float* W2 = (const float*)d_in[15];
    const float* b2 = (const float*)d_in[16];
    const float* g1 = (const float*)d_in[17];
    const float* be1 = (const float*)d_in[18];
    const float* g2 = (const float*)d_in[19];
    const float* be2 = (const float*)d_in[20];
    float* out = (float*)d_out;

    char* ws = (char*)d_ws;
    const size_t O_SRCBF = 0;                        // 8.39 MB (reused: attn_bf)
    const size_t O_QKV   = 8388608;                  // 25.17 MB
    const size_t O_XBF   = 33554432;                 // 8.39 MB
    const size_t O_WQKV  = 41943040;                 // 0.39 MB
    const size_t O_WO    = O_WQKV + 768 * 256 * 2;
    const size_t O_W1    = O_WO + 256 * 256 * 2;
    const size_t O_W2    = O_W1 + (size_t)DFF * 256 * 2;
    const size_t O_BQKV  = O_W2 + (size_t)DFF * 256 * 2;
    const size_t O_H     = O_BQKV + 4096;            // hidden buffer

    __hip_bfloat16* src_bf  = (__hip_bfloat16*)(ws + O_SRCBF);
    __hip_bfloat16* attn_bf = (__hip_bfloat16*)(ws + O_SRCBF);
    __hip_bfloat16* qkv     = (__hip_bfloat16*)(ws + O_QKV);
    __hip_bfloat16* x_bf    = (__hip_bfloat16*)(ws + O_XBF);
    __hip_bfloat16* WqkvT   = (__hip_bfloat16*)(ws + O_WQKV);
    __hip_bfloat16* WoT     = (__hip_bfloat16*)(ws + O_WO);
    __hip_bfloat16* W1T     = (__hip_bfloat16*)(ws + O_W1);
    __hip_bfloat16* W2T     = (__hip_bfloat16*)(ws + O_W2);
    float*          bqkv    = (float*)(ws + O_BQKV);
    __hip_bfloat16* hc      = (__hip_bfloat16*)(ws + O_H);

    const bool fused_ffn = ws_size >= O_H + (size_t)N_TOK * DFF * 2;

    const dim3 blk(256);
    const float qscale = 0.17677669529663687f;

    // --- conversions ---
    cvt_f2b<<<N_TOK * D_MODEL / 4 / 256, blk, 0, stream>>>(src, src_bf, N_TOK * D_MODEL);
    cvt_w3_tiled<<<dim3(24, 8), blk, 0, stream>>>(Wq, Wk, Wv, WqkvT, qscale);
    cvt_wt_tiled<<<dim3(8, 8),  blk, 0, stream>>>(Wo, WoT, 256, 256, 1.0f);
    cvt_wt_tiled<<<dim3(64, 8), blk, 0, stream>>>(W1, W1T, 256, DFF, 1.0f);
    cvt_wt_tiled<<<dim3(8, 64), blk, 0, stream>>>(W2, W2T, DFF, 256, 1.0f);
    make_bqkv<<<1, 768, 0, stream>>>(bq, bk, bv, bqkv, qscale);

    // --- fused QKV projection ---
    gemm_bt<<<dim3(6, 128), blk, 0, stream>>>(src_bf, 256, WqkvT, 256, bqkv,
                                              nullptr, nullptr, nullptr, qkv,
                                              N_TOK, 768, 256, 0, 0);
    // --- gathered attention ---
    attn_kernel<<<N_TOK, blk, 0, stream>>>(qkv, index_pair, kbc, ipb, attn_bf);

    // --- Wo + residual(src) + LN1 fused -> x_bf ---
    gemm_bt_ln8<<<dim3(N_TOK / 64), dim3(512), 0, stream>>>(
        attn_bf, 256, WoT, 256, bo, src, nullptr, g1, be1,
        nullptr, x_bf, 256);

    if (fused_ffn) {
        // --- FFN1 (single dispatch, N=2048, relu) ---
        gemm_bt<<<dim3(16, 128), blk, 0, stream>>>(
            x_bf, 256, W1T, 256, b1, nullptr, nullptr, nullptr, hc,
            N_TOK, DFF, 256, 1, 0);
        // --- FFN2 + residual(x_bf) + LN2 fused -> out ---
        gemm_bt_ln8<<<dim3(N_TOK / 64), dim3(512), 0, stream>>>(
            hc, DFF, W2T, DFF, b2, nullptr, x_bf, g2, be2,
            out, nullptr, DFF);
    } else {
        // fallback: chunked FFN + separate LN2
        float* zb = (float*)(ws + O_H + (size_t)N_TOK * 512 * 2);
        const int ffc = 512;
        for (int c = 0; c < DFF / ffc; ++c) {
            gemm_bt<<<dim3(ffc / 128, 128), blk, 0, stream>>>(
                x_bf, 256, W1T + (size_t)c * ffc * 256, 256,
                b1 + c * ffc, nullptr, nullptr, nullptr, hc,
                N_TOK, ffc, 256, 1, 0);
            gemm_bt64<<<dim3(2, 256), blk, 0, stream>>>(
                hc, ffc, W2T + (size_t)c * ffc, DFF,
                (c == 0) ? b2 : nullptr, nullptr, (c == 0) ? x_bf : nullptr,
                zb, nullptr, N_TOK, 256, ffc, 0, (c > 0) ? 1 : 0);
        }
        ln_kernel<<<N_TOK, blk, 0, stream>>>(zb, g2, be2, out, nullptr);
    }
}